// Round 17
// baseline (225.648 us; speedup 1.0000x reference)
//
#include <hip/hip_runtime.h>
#include <hip/hip_fp16.h>
#include <math.h>

#define NN 100000
#define NE 1600000
#define EPS_BN 1e-5f
#define EPS_NORM 1e-12f
#define SLOPE 0.01f
#define NBUCK 391                            // = ceil(NN/256); bucket = dst>>8
#define NBLK 1563                            // edge-chunk blocks (1024 edges each)
#define CNT_LEN (NBUCK * NBLK)               // 611,133
#define CSB ((CNT_LEN + 255) / 256)          // 2388
#define GS_LEN (64 * NBUCK)                  // 25024
#define GS_BLOCKS ((GS_LEN + 255) / 256)     // 98

typedef _Float16 h2 __attribute__((ext_vector_type(2)));

#if __has_builtin(__builtin_amdgcn_exp2f)
#define EXP2F(x) __builtin_amdgcn_exp2f(x)
#else
#define EXP2F(x) exp2f(x)
#endif

__device__ __forceinline__ float fast_tanh(float x) {
    float t = EXP2F(x * 2.885390082f);
    return fmaf(-2.0f, __builtin_amdgcn_rcpf(t + 1.0f), 1.0f);
}

__device__ __forceinline__ unsigned pk2(float a, float b) {
    union { __half2 h; unsigned u; } c;
    c.h = __float22half2_rn(make_float2(a, b));
    return c.u;
}

__device__ __forceinline__ h2 u2h(unsigned x) {
    union { unsigned u; h2 h; } c; c.u = x; return c.h;
}

#if __has_builtin(__builtin_amdgcn_fdot2)
#define FDOT2(A, B, C) __builtin_amdgcn_fdot2((A), (B), (C), false)
#else
__device__ __forceinline__ float FDOT2(h2 a, h2 b, float c) {
    return fmaf((float)a.x, (float)b.x, fmaf((float)a.y, (float)b.y, c));
}
#endif

// R1: per-block LDS bucket histogram (bucket = dst>>8). No global atomics.
__global__ void __launch_bounds__(256) r1_count_kernel(
    const int* __restrict__ ei, int* __restrict__ cntT)
{
    __shared__ int h[NBUCK];
    int b = blockIdx.x, t = threadIdx.x;
    for (int j = t; j < NBUCK; j += 256) h[j] = 0;
    __syncthreads();
    int e4 = b * 1024 + t * 4;
    if (e4 < NE) {
        int4 d4 = *(const int4*)(ei + NE + e4);
        atomicAdd(&h[d4.x >> 8], 1);
        atomicAdd(&h[d4.y >> 8], 1);
        atomicAdd(&h[d4.z >> 8], 1);
        atomicAdd(&h[d4.w >> 8], 1);
    }
    __syncthreads();
    for (int j = t; j < NBUCK; j += 256) cntT[(size_t)j * NBLK + b] = h[j];
}

// Generic 2-level exclusive scan (block pass + offset pass), length-param'd.
__global__ void __launch_bounds__(256) gscanA_kernel(
    int* __restrict__ a, int* __restrict__ bs, int len)
{
    int b = blockIdx.x, t = threadIdx.x;
    int i = b * 256 + t;
    int d = (i < len) ? a[i] : 0;
    __shared__ int sh[256];
    sh[t] = d;
    __syncthreads();
    for (int off = 1; off < 256; off <<= 1) {
        int val = (t >= off) ? sh[t - off] : 0;
        __syncthreads();
        sh[t] += val;
        __syncthreads();
    }
    if (i < len) a[i] = sh[t] - d;
    if (t == 255) bs[b] = sh[255];
}

__global__ void __launch_bounds__(256) gscanB_kernel(
    int* __restrict__ a, const int* __restrict__ bs, int len)
{
    int b = blockIdx.x, t = threadIdx.x;
    __shared__ int sh[256];
    int s = 0;
    for (int j = t; j < b; j += 256) s += bs[j];
    sh[t] = s;
    __syncthreads();
    for (int off = 128; off > 0; off >>= 1) {
        if (t < off) sh[t] += sh[t + off];
        __syncthreads();
    }
    int boff = sh[0];
    int i = b * 256 + t;
    if (i < len) a[i] += boff;
}

// R2: bucket-scatter packed recs [dst:17|src:17|a0:15|a1:15] via LDS ranks.
__global__ void __launch_bounds__(256) r2_scatter_kernel(
    const int* __restrict__ ei, const float* __restrict__ ea,
    const int* __restrict__ cntT, unsigned long long* __restrict__ bucketed)
{
    __shared__ int h[NBUCK];
    __shared__ int base[NBUCK];
    int b = blockIdx.x, t = threadIdx.x;
    for (int j = t; j < NBUCK; j += 256) {
        h[j] = 0;
        base[j] = cntT[(size_t)j * NBLK + b];
    }
    __syncthreads();
    int e4 = b * 1024 + t * 4;
    if (e4 < NE) {
        int4 s4 = *(const int4*)(ei + e4);
        int4 d4 = *(const int4*)(ei + NE + e4);
        float4 a01 = *(const float4*)(ea + 2 * (size_t)e4);
        float4 a23 = *(const float4*)(ea + 2 * (size_t)e4 + 4);
#define DO_EDGE(S, D, A0, A1)                                                \
        {                                                                    \
            unsigned a0q = __float2uint_rn((A0) * 32768.0f);                 \
            if (a0q > 32767u) a0q = 32767u;                                  \
            unsigned a1q = __float2uint_rn((A1) * 32768.0f);                 \
            if (a1q > 32767u) a1q = 32767u;                                  \
            unsigned long long rec =                                         \
                  (((unsigned long long)(unsigned)(D)) << 47)                \
                | (((unsigned long long)(unsigned)(S)) << 30)                \
                | (((unsigned long long)a0q) << 15)                          \
                | ((unsigned long long)a1q);                                 \
            int bb = (D) >> 8;                                               \
            int lr = atomicAdd(&h[bb], 1);                                   \
            bucketed[base[bb] + lr] = rec;                                   \
        }
        DO_EDGE(s4.x, d4.x, a01.x, a01.y)
        DO_EDGE(s4.y, d4.y, a01.z, a01.w)
        DO_EDGE(s4.z, d4.z, a23.x, a23.y)
        DO_EDGE(s4.w, d4.w, a23.z, a23.w)
#undef DO_EDGE
    }
}

// R3 FUSED: per-bucket finalize + expand + moments. 512 threads/bucket.
// Pass 1: LDS node hist + rank -> rowptr, LPT pr/bhT.
// Pass 2: compute e once/edge, write A16/B8 at final sorted pos, accumulate
// 77 moments via even/odd lane-pair split + shfl_xor exchange (no spill).
__global__ void __launch_bounds__(512) finalize_kernel(
    const unsigned long long* __restrict__ bucketed,
    const int* __restrict__ cntT,
    const float* __restrict__ v,
    uint4* __restrict__ A16, uint2* __restrict__ B8,
    int* __restrict__ rowptr, int* __restrict__ pr, int* __restrict__ bhT,
    float* __restrict__ partials)   // [NBUCK][77]
{
    __shared__ int hist[256], lps[256], lh[64];
    __shared__ unsigned short pos16[6144];
    __shared__ float lsum[8][77];
    int b = blockIdx.x, t = threadIdx.x;
    if (t < 256) hist[t] = 0;
    if (t < 64) lh[t] = 0;
    __syncthreads();
    int bstart = cntT[(size_t)b * NBLK];
    int bend = (b == NBUCK - 1) ? NE : cntT[(size_t)(b + 1) * NBLK];

    for (int j = bstart + t; j < bend; j += 512) {
        unsigned long long r = bucketed[j];
        int dl = (int)((r >> 47) & 255u);
        int lr = atomicAdd(&hist[dl], 1);
        int o = j - bstart;
        if (o < 6144) pos16[o] = (unsigned short)lr;
    }
    __syncthreads();
    int d = (t < 256) ? hist[t] : 0;
    if (t < 256) lps[t] = d;
    __syncthreads();
    for (int off = 1; off < 256; off <<= 1) {
        int val = (t >= off && t < 256) ? lps[t - off] : 0;
        __syncthreads();
        if (t < 256) lps[t] += val;
        __syncthreads();
    }
    int node = b * 256 + t;
    if (t < 256 && node < NN) {
        rowptr[node] = bstart + lps[t] - d;
        int db = d < 63 ? d : 63;
        int bkt = 63 - db;                   // descending degree (LPT)
        int lr2 = atomicAdd(&lh[bkt], 1);
        pr[node] = (lr2 << 6) | bkt;
    }
    if (b == 0 && t == 0) rowptr[NN] = NE;
    __syncthreads();
    if (t < 64) bhT[t * NBUCK + b] = lh[t];

    // pass 2: expand + moments
    float acc[39];
#pragma unroll
    for (int i = 0; i < 39; ++i) acc[i] = 0.0f;

    for (int j = bstart + t; (j - (t & 1)) < bend; j += 512) {
        bool valid = j < bend;
        float e[11];
        if (valid) {
            unsigned long long r = bucketed[j];
            int dl = (int)((r >> 47) & 255u);
            int s = (int)((r >> 30) & 0x1FFFFu);
            float a0 = (float)(unsigned)((r >> 15) & 0x7FFFu) * (1.0f / 32768.0f);
            float a1 = (float)(unsigned)(r & 0x7FFFu) * (1.0f / 32768.0f);
            int dn = b * 256 + dl;
            float4 s0 = *(const float4*)(v + (size_t)s * 8);
            float4 s1 = *(const float4*)(v + (size_t)s * 8 + 4);
            float4 d0 = *(const float4*)(v + (size_t)dn * 8);
            float4 d1 = *(const float4*)(v + (size_t)dn * 8 + 4);
            float df[8];
            df[0] = d0.x - s0.x; df[1] = d0.y - s0.y;
            df[2] = d0.z - s0.z; df[3] = d0.w - s0.w;
            df[4] = d1.x - s1.x; df[5] = d1.y - s1.y;
            df[6] = d1.z - s1.z; df[7] = d1.w - s1.w;
            float nsq = 0.0f;
#pragma unroll
            for (int q = 0; q < 8; ++q) nsq = fmaf(df[q], df[q], nsq);
            float nrm = sqrtf(nsq);
            float inv = __builtin_amdgcn_rcpf(nrm + EPS_NORM);
            e[0] = a0; e[1] = a1; e[2] = nrm;
#pragma unroll
            for (int q = 0; q < 8; ++q) e[3 + q] = df[q] * inv;

            int o = j - bstart;
            int lr = (o < 6144) ? (int)pos16[o] : 0;
            int pos = bstart + (lps[dl] - hist[dl]) + lr;
            uint4 lo;
            lo.x = pk2(e[0], e[1]); lo.y = pk2(e[2], e[3]);
            lo.z = pk2(e[4], e[5]); lo.w = pk2(e[6], e[7]);
            A16[pos] = lo;
            unsigned q10 = __float2uint_rn((e[10] + 1.0f) * 16383.5f);
            if (q10 > 32767u) q10 = 32767u;
            uint2 hv;
            hv.x = pk2(e[8], e[9]);
            hv.y = ((unsigned)s << 15) | q10;
            B8[pos] = hv;
        } else {
#pragma unroll
            for (int k = 0; k < 11; ++k) e[k] = 0.0f;
        }
        float eo[11];
#pragma unroll
        for (int k = 0; k < 11; ++k) eo[k] = __shfl_xor(e[k], 1);
        if (!(t & 1)) {
#pragma unroll
            for (int k = 0; k < 11; ++k) acc[k] += e[k] + eo[k];
            int p = 11;
#pragma unroll
            for (int k = 0; k < 11; ++k)
#pragma unroll
                for (int l = k; l < 11; ++l) {
                    if (p < 39) {
                        acc[p] = fmaf(e[k], e[l], acc[p]);
                        acc[p] = fmaf(eo[k], eo[l], acc[p]);
                    }
                    ++p;
                }
        } else {
            int p = 11;
#pragma unroll
            for (int k = 0; k < 11; ++k)
#pragma unroll
                for (int l = k; l < 11; ++l) {
                    if (p >= 39) {
                        acc[p - 39] = fmaf(e[k], e[l], acc[p - 39]);
                        acc[p - 39] = fmaf(eo[k], eo[l], acc[p - 39]);
                    }
                    ++p;
                }
        }
    }

    // parity-preserving butterfly: lane0 sums even lanes, lane1 odd lanes.
#pragma unroll
    for (int i = 0; i < 39; ++i) {
        float x = acc[i];
        x += __shfl_down(x, 2);
        x += __shfl_down(x, 4);
        x += __shfl_down(x, 8);
        x += __shfl_down(x, 16);
        x += __shfl_down(x, 32);
        acc[i] = x;
    }
    int wave = t >> 6;
    int lane = t & 63;
    if (lane == 0) {
#pragma unroll
        for (int i = 0; i < 39; ++i) lsum[wave][i] = acc[i];
    }
    if (lane == 1) {
#pragma unroll
        for (int i = 0; i < 38; ++i) lsum[wave][39 + i] = acc[i];
    }
    __syncthreads();
    if (t < 77) {
        float s = 0.0f;
#pragma unroll
        for (int w = 0; w < 8; ++w) s += lsum[w][t];
        partials[b * 77 + t] = s;
    }
}

// BN closed-form; fold scale into W'/b'; emit f16-pair packed weights (5 rows).
__global__ void bn_finalize_kernel(
    const float* __restrict__ partials,
    const float* __restrict__ w0, const float* __restrict__ b0,
    const float* __restrict__ g0, const float* __restrict__ be0,
    const float* __restrict__ w1, const float* __restrict__ b1,
    const float* __restrict__ g1, const float* __restrict__ be1,
    float* __restrict__ wbp)   // layer l at +l*1152: W'[704], b'[64], pk[320]
{
    __shared__ double gs[77];
    int t = threadIdx.x;
    if (t < 77) {
        double s = 0.0;
        for (int b = 0; b < NBUCK; ++b) s += (double)partials[b * 77 + t];
        gs[t] = s;
    }
    __syncthreads();
    if (t >= 128) return;
    int layer = t >> 6;
    int c = t & 63;
    const float* W  = layer ? w1 : w0;
    const float* B  = layer ? b1 : b0;
    const float* G  = layer ? g1 : g0;
    const float* BE = layer ? be1 : be0;

    const double invE = 1.0 / (double)NE;
    double m[11], wv[11];
    for (int k = 0; k < 11; ++k) {
        m[k] = gs[k] * invE;
        wv[k] = (double)W[k * 64 + c];
    }
    double md = 0.0;
    for (int k = 0; k < 11; ++k) md += m[k] * wv[k];
    double s2 = 0.0;
    int p = 11;
    for (int k = 0; k < 11; ++k)
        for (int l = k; l < 11; ++l) {
            double Me = gs[p] * invE; ++p;
            double term = Me * wv[k] * wv[l];
            s2 += (k == l) ? term : 2.0 * term;
        }
    double var = s2 - md * md;
    double mu = md + (double)B[c];
    float scale = (float)((double)G[c] / sqrt(var + (double)EPS_BN));
    float shift = (float)((double)BE[c] - mu * (double)scale);

    float* wpd = wbp + layer * 1152;
    for (int k = 0; k < 11; ++k) wpd[k * 64 + c] = W[k * 64 + c] * scale;
    wpd[704 + c] = fmaf(B[c], scale, shift);
    unsigned* pw = (unsigned*)(wpd + 768);
    for (int kp = 0; kp < 5; ++kp) {
        float wlo = W[(2 * kp) * 64 + c] * scale;
        float whi = W[(2 * kp + 1) * 64 + c] * scale;
        pw[kp * 64 + c] = pk2(wlo, whi);
    }
}

__global__ void __launch_bounds__(256) permB_kernel(
    const int* __restrict__ pr, const int* __restrict__ bhT,
    const int* __restrict__ rowptr, int4* __restrict__ perm4)
{
    int n = blockIdx.x * 256 + threadIdx.x;
    if (n >= NN) return;
    int p = pr[n];
    int bkt = p & 63, lrank = p >> 6, b = n >> 8;
    int pos = bhT[bkt * NBUCK + b] + lrank;
    perm4[pos] = make_int4(n, rowptr[n], rowptr[n + 1], 0);
}

// Edge body: e-pairs from A16/B8, packed f16 weights + f32 row 10.
#define FAT_BODY3(LO, HB, E10, XI)                                           \
    do {                                                                     \
        h2 ep0 = u2h((LO).x), ep1 = u2h((LO).y);                             \
        h2 ep2 = u2h((LO).z), ep3 = u2h((LO).w);                             \
        h2 ep4 = u2h((HB).x);                                                \
        _Pragma("unroll")                                                    \
        for (int o = 0; o < 8; ++o) {                                        \
            float hh = breg[o];                                              \
            hh = FDOT2(ep0, pw[0][o], hh);                                   \
            hh = FDOT2(ep1, pw[1][o], hh);                                   \
            hh = FDOT2(ep2, pw[2][o], hh);                                   \
            hh = FDOT2(ep3, pw[3][o], hh);                                   \
            hh = FDOT2(ep4, pw[4][o], hh);                                   \
            hh = fmaf((E10), w10[o], hh);                                    \
            msg[o] = fmaf((XI), fast_tanh(hh), msg[o]);                      \
        }                                                                    \
    } while (0)

// Per-layer fused gather-message + mean + root + lrelu (+residual).
template<int LAYER>
__global__ void __launch_bounds__(256)
__attribute__((amdgpu_waves_per_eu(2, 6))) layer_fat_kernel(
    const float* __restrict__ vres,
    const float* __restrict__ x,
    const uint4* __restrict__ A16, const uint2* __restrict__ B8,
    const int4* __restrict__ perm4,
    const float* __restrict__ wb,   // layer base: W'f32[704], b'[64], pk[320]
    const float* __restrict__ rw, const float* __restrict__ rb,
    float* __restrict__ out)
{
    int g = blockIdx.x * 256 + threadIdx.x;
    int4 pm = perm4[g >> 3];
    int n = pm.x, rp0 = pm.y, rp1 = pm.z;
    int i = g & 7;

    h2 pw[5][8];
    const unsigned* pwg = (const unsigned*)(wb + 768);
#pragma unroll
    for (int kp = 0; kp < 5; ++kp) {
        uint4 pa = *(const uint4*)(pwg + kp * 64 + i * 8);
        uint4 pb = *(const uint4*)(pwg + kp * 64 + i * 8 + 4);
        pw[kp][0] = u2h(pa.x); pw[kp][1] = u2h(pa.y);
        pw[kp][2] = u2h(pa.z); pw[kp][3] = u2h(pa.w);
        pw[kp][4] = u2h(pb.x); pw[kp][5] = u2h(pb.y);
        pw[kp][6] = u2h(pb.z); pw[kp][7] = u2h(pb.w);
    }
    float w10[8];
    {
        float4 wa = *(const float4*)(wb + 640 + i * 8);
        float4 wc = *(const float4*)(wb + 640 + i * 8 + 4);
        w10[0] = wa.x; w10[1] = wa.y; w10[2] = wa.z; w10[3] = wa.w;
        w10[4] = wc.x; w10[5] = wc.y; w10[6] = wc.z; w10[7] = wc.w;
    }
    float breg[8];
    {
        float4 ba = *(const float4*)(wb + 704 + i * 8);
        float4 bb = *(const float4*)(wb + 704 + i * 8 + 4);
        breg[0] = ba.x; breg[1] = ba.y; breg[2] = ba.z; breg[3] = ba.w;
        breg[4] = bb.x; breg[5] = bb.y; breg[6] = bb.z; breg[7] = bb.w;
    }

    float4 vd0 = *(const float4*)(vres + (size_t)n * 8);
    float4 vd1 = *(const float4*)(vres + (size_t)n * 8 + 4);
    float vd[8] = {vd0.x, vd0.y, vd0.z, vd0.w, vd1.x, vd1.y, vd1.z, vd1.w};

    float msg[8];
#pragma unroll
    for (int o = 0; o < 8; ++o) msg[o] = 0.0f;

    int j = rp0;
    for (; j + 2 <= rp1; j += 2) {
        uint4 lo0 = A16[j];
        uint4 lo1 = A16[j + 1];
        uint2 hb0 = B8[j];
        uint2 hb1 = B8[j + 1];
        int s0 = (int)(hb0.y >> 15);
        int s1 = (int)(hb1.y >> 15);
        float e10a = fmaf((float)(hb0.y & 0x7FFFu), 1.0f / 16383.5f, -1.0f);
        float e10b = fmaf((float)(hb1.y & 0x7FFFu), 1.0f / 16383.5f, -1.0f);
        float xi0 = x[(size_t)s0 * 8 + i];
        float xi1 = x[(size_t)s1 * 8 + i];
        FAT_BODY3(lo0, hb0, e10a, xi0);
        FAT_BODY3(lo1, hb1, e10b, xi1);
    }
    if (j < rp1) {
        uint4 lo0 = A16[j];
        uint2 hb0 = B8[j];
        int s0 = (int)(hb0.y >> 15);
        float e10a = fmaf((float)(hb0.y & 0x7FFFu), 1.0f / 16383.5f, -1.0f);
        float xi0 = x[(size_t)s0 * 8 + i];
        FAT_BODY3(lo0, hb0, e10a, xi0);
    }

#pragma unroll
    for (int o = 0; o < 8; ++o) {
        float m = msg[o];
        m += __shfl_xor(m, 1);
        m += __shfl_xor(m, 2);
        m += __shfl_xor(m, 4);
        msg[o] = m;
    }
    float mo = msg[0];
#pragma unroll
    for (int o = 1; o < 8; ++o) if (i == o) mo = msg[o];

    float cf = (float)(rp1 - rp0);
    float invc = __builtin_amdgcn_rcpf(fmaxf(cf, 1.0f));

    float xn[8];
    if (LAYER == 0) {
#pragma unroll
        for (int q = 0; q < 8; ++q) xn[q] = vd[q];
    } else {
        float4 x0 = *(const float4*)(x + (size_t)n * 8);
        float4 x1 = *(const float4*)(x + (size_t)n * 8 + 4);
        xn[0] = x0.x; xn[1] = x0.y; xn[2] = x0.z; xn[3] = x0.w;
        xn[4] = x1.x; xn[5] = x1.y; xn[6] = x1.z; xn[7] = x1.w;
    }
    float a = fmaf(mo, invc, rb[i]);
#pragma unroll
    for (int k = 0; k < 8; ++k) a = fmaf(xn[k], rw[k * 8 + i], a);
    float y = (a > 0.0f) ? a : SLOPE * a;
    if (LAYER == 1) y += vres[(size_t)n * 8 + i];
    out[(size_t)n * 8 + i] = y;
}

extern "C" void kernel_launch(void* const* d_in, const int* in_sizes, int n_in,
                              void* d_out, int out_size, void* d_ws, size_t ws_size,
                              hipStream_t stream) {
    const float* v  = (const float*)d_in[0];
    const int* ei   = (const int*)d_in[1];
    const float* ea = (const float*)d_in[2];
    const float* en_w0  = (const float*)d_in[3];
    const float* en_b0  = (const float*)d_in[4];
    const float* en_g0  = (const float*)d_in[5];
    const float* en_be0 = (const float*)d_in[6];
    const float* rw0    = (const float*)d_in[7];
    const float* rb0    = (const float*)d_in[8];
    const float* en_w1  = (const float*)d_in[9];
    const float* en_b1  = (const float*)d_in[10];
    const float* en_g1  = (const float*)d_in[11];
    const float* en_be1 = (const float*)d_in[12];
    const float* rw1    = (const float*)d_in[13];
    const float* rb1    = (const float*)d_in[14];

    char* ws = (char*)d_ws;
    float* partials = (float*)(ws);                    // 391*77*4 = 120,428 B
    float* wbp      = (float*)(ws + 131072);           // 9,216 B
    int*   rowptr   = (int*)  (ws + 143360);           // 400,004 B
    int*   pr       = (int*)  (ws + 543744);           // 400,000 B
    int4*  perm4    = (int4*) (ws + 944128);           // 1,600,000 B
    int*   bhT      = (int*)  (ws + 2544128);          // 100,096 B
    int*   gbsum    = (int*)  (ws + 2644224);          // 392 B
    int*   cbsum    = (int*)  (ws + 2644736);          // 9,552 B
    int*   cntT     = (int*)  (ws + 2654336);          // 2,444,532 B -> 5,098,868
    float* v1       = (float*)(ws + 5099008);          // 3,200,000 B -> 8,299,008
    unsigned long long* bucketed = (unsigned long long*)(ws + 8299520); // 12.8 MB -> 21,099,520
    uint4* A16      = (uint4*)(ws + 21099520);         // 25.6 MB -> 46,699,520
    uint2* B8       = (uint2*)(ws + 46699520);         // 12.8 MB -> 59,499,520
    float* vout     = (float*)d_out;

    r1_count_kernel<<<NBLK, 256, 0, stream>>>(ei, cntT);
    gscanA_kernel<<<CSB, 256, 0, stream>>>(cntT, cbsum, CNT_LEN);
    gscanB_kernel<<<CSB, 256, 0, stream>>>(cntT, cbsum, CNT_LEN);
    r2_scatter_kernel<<<NBLK, 256, 0, stream>>>(ei, ea, cntT, bucketed);
    finalize_kernel<<<NBUCK, 512, 0, stream>>>(bucketed, cntT, v, A16, B8,
                                               rowptr, pr, bhT, partials);
    gscanA_kernel<<<GS_BLOCKS, 256, 0, stream>>>(bhT, gbsum, GS_LEN);
    gscanB_kernel<<<GS_BLOCKS, 256, 0, stream>>>(bhT, gbsum, GS_LEN);
    permB_kernel<<<NBUCK, 256, 0, stream>>>(pr, bhT, rowptr, perm4);
    bn_finalize_kernel<<<1, 128, 0, stream>>>(partials, en_w0, en_b0, en_g0, en_be0,
                                              en_w1, en_b1, en_g1, en_be1, wbp);

    const int LB = (NN * 8) / 256;   // 3125, exact
    layer_fat_kernel<0><<<LB, 256, 0, stream>>>(v, v,  A16, B8, perm4, wbp,        rw0, rb0, v1);
    layer_fat_kernel<1><<<LB, 256, 0, stream>>>(v, v1, A16, B8, perm4, wbp + 1152, rw1, rb1, vout);
}

// Round 18
// 216.543 us; speedup vs baseline: 1.0420x; 1.0420x over previous
//
#include <hip/hip_runtime.h>
#include <hip/hip_fp16.h>
#include <math.h>

#define NN 100000
#define NE 1600000
#define EPS_BN 1e-5f
#define EPS_NORM 1e-12f
#define SLOPE 0.01f
#define NBUCK 391                            // = ceil(NN/256); bucket = dst>>8
#define NBLK 391                             // edge-chunk blocks (4096 edges each)
#define EPB 4096                             // edges per r1/r2 block
#define CNT_LEN (NBUCK * NBLK)               // 152,881
#define CSB ((CNT_LEN + 255) / 256)          // 598
#define GS_LEN (64 * NBUCK)                  // 25024
#define GS_BLOCKS ((GS_LEN + 255) / 256)     // 98

typedef _Float16 h2 __attribute__((ext_vector_type(2)));

#if __has_builtin(__builtin_amdgcn_exp2f)
#define EXP2F(x) __builtin_amdgcn_exp2f(x)
#else
#define EXP2F(x) exp2f(x)
#endif

__device__ __forceinline__ float fast_tanh(float x) {
    float t = EXP2F(x * 2.885390082f);
    return fmaf(-2.0f, __builtin_amdgcn_rcpf(t + 1.0f), 1.0f);
}

__device__ __forceinline__ unsigned pk2(float a, float b) {
    union { __half2 h; unsigned u; } c;
    c.h = __float22half2_rn(make_float2(a, b));
    return c.u;
}

__device__ __forceinline__ h2 u2h(unsigned x) {
    union { unsigned u; h2 h; } c; c.u = x; return c.h;
}

#if __has_builtin(__builtin_amdgcn_fdot2)
#define FDOT2(A, B, C) __builtin_amdgcn_fdot2((A), (B), (C), false)
#else
__device__ __forceinline__ float FDOT2(h2 a, h2 b, float c) {
    return fmaf((float)a.x, (float)b.x, fmaf((float)a.y, (float)b.y, c));
}
#endif

// R1: per-block LDS bucket histogram over 4096 edges (bucket = dst>>8).
__global__ void __launch_bounds__(256) r1_count_kernel(
    const int* __restrict__ ei, int* __restrict__ cntT)
{
    __shared__ int h[NBUCK];
    int b = blockIdx.x, t = threadIdx.x;
    for (int j = t; j < NBUCK; j += 256) h[j] = 0;
    __syncthreads();
#pragma unroll
    for (int it = 0; it < 4; ++it) {
        int e4 = b * EPB + it * 1024 + t * 4;
        if (e4 < NE) {
            int4 d4 = *(const int4*)(ei + NE + e4);
            atomicAdd(&h[d4.x >> 8], 1);
            atomicAdd(&h[d4.y >> 8], 1);
            atomicAdd(&h[d4.z >> 8], 1);
            atomicAdd(&h[d4.w >> 8], 1);
        }
    }
    __syncthreads();
    for (int j = t; j < NBUCK; j += 256) cntT[(size_t)j * NBLK + b] = h[j];
}

// Generic 2-level exclusive scan (block pass + offset pass), length-param'd.
__global__ void __launch_bounds__(256) gscanA_kernel(
    int* __restrict__ a, int* __restrict__ bs, int len)
{
    int b = blockIdx.x, t = threadIdx.x;
    int i = b * 256 + t;
    int d = (i < len) ? a[i] : 0;
    __shared__ int sh[256];
    sh[t] = d;
    __syncthreads();
    for (int off = 1; off < 256; off <<= 1) {
        int val = (t >= off) ? sh[t - off] : 0;
        __syncthreads();
        sh[t] += val;
        __syncthreads();
    }
    if (i < len) a[i] = sh[t] - d;
    if (t == 255) bs[b] = sh[255];
}

__global__ void __launch_bounds__(256) gscanB_kernel(
    int* __restrict__ a, const int* __restrict__ bs, int len)
{
    int b = blockIdx.x, t = threadIdx.x;
    __shared__ int sh[256];
    int s = 0;
    for (int j = t; j < b; j += 256) s += bs[j];
    sh[t] = s;
    __syncthreads();
    for (int off = 128; off > 0; off >>= 1) {
        if (t < off) sh[t] += sh[t + off];
        __syncthreads();
    }
    int boff = sh[0];
    int i = b * 256 + t;
    if (i < len) a[i] += boff;
}

// R2: bucket-scatter packed recs [dst:17|src:17|a0:15|a1:15] via LDS ranks.
__global__ void __launch_bounds__(256) r2_scatter_kernel(
    const int* __restrict__ ei, const float* __restrict__ ea,
    const int* __restrict__ cntT, unsigned long long* __restrict__ bucketed)
{
    __shared__ int h[NBUCK];
    __shared__ int base[NBUCK];
    int b = blockIdx.x, t = threadIdx.x;
    for (int j = t; j < NBUCK; j += 256) {
        h[j] = 0;
        base[j] = cntT[(size_t)j * NBLK + b];
    }
    __syncthreads();
#pragma unroll
    for (int it = 0; it < 4; ++it) {
        int e4 = b * EPB + it * 1024 + t * 4;
        if (e4 < NE) {
            int4 s4 = *(const int4*)(ei + e4);
            int4 d4 = *(const int4*)(ei + NE + e4);
            float4 a01 = *(const float4*)(ea + 2 * (size_t)e4);
            float4 a23 = *(const float4*)(ea + 2 * (size_t)e4 + 4);
#define DO_EDGE(S, D, A0, A1)                                                \
            {                                                                \
                unsigned a0q = __float2uint_rn((A0) * 32768.0f);             \
                if (a0q > 32767u) a0q = 32767u;                              \
                unsigned a1q = __float2uint_rn((A1) * 32768.0f);             \
                if (a1q > 32767u) a1q = 32767u;                              \
                unsigned long long rec =                                     \
                      (((unsigned long long)(unsigned)(D)) << 47)            \
                    | (((unsigned long long)(unsigned)(S)) << 30)            \
                    | (((unsigned long long)a0q) << 15)                      \
                    | ((unsigned long long)a1q);                             \
                int bb = (D) >> 8;                                           \
                int lr = atomicAdd(&h[bb], 1);                               \
                bucketed[base[bb] + lr] = rec;                               \
            }
            DO_EDGE(s4.x, d4.x, a01.x, a01.y)
            DO_EDGE(s4.y, d4.y, a01.z, a01.w)
            DO_EDGE(s4.z, d4.z, a23.x, a23.y)
            DO_EDGE(s4.w, d4.w, a23.z, a23.w)
#undef DO_EDGE
        }
    }
}

// R3 FUSED: per-bucket finalize + expand + moments. 512 threads/bucket.
// waves_per_eu(2,4): acc[39]+e[11]+eo[11] must stay RESIDENT (r17's VGPR=44
// spill put 55MB of scratch on HBM; WRITE 93MB, VALUBusy 17%).
__global__ void __launch_bounds__(512)
__attribute__((amdgpu_waves_per_eu(2, 4))) finalize_kernel(
    const unsigned long long* __restrict__ bucketed,
    const int* __restrict__ cntT,
    const float* __restrict__ v,
    uint4* __restrict__ A16, uint2* __restrict__ B8,
    int* __restrict__ rowptr, int* __restrict__ pr, int* __restrict__ bhT,
    float* __restrict__ partials)   // [NBUCK][77]
{
    __shared__ int hist[256], lps[256], lh[64];
    __shared__ unsigned short pos16[6144];
    __shared__ float lsum[8][77];
    int b = blockIdx.x, t = threadIdx.x;
    if (t < 256) hist[t] = 0;
    if (t < 64) lh[t] = 0;
    __syncthreads();
    int bstart = cntT[(size_t)b * NBLK];
    int bend = (b == NBUCK - 1) ? NE : cntT[(size_t)(b + 1) * NBLK];

    for (int j = bstart + t; j < bend; j += 512) {
        unsigned long long r = bucketed[j];
        int dl = (int)((r >> 47) & 255u);
        int lr = atomicAdd(&hist[dl], 1);
        int o = j - bstart;
        if (o < 6144) pos16[o] = (unsigned short)lr;
    }
    __syncthreads();
    int d = (t < 256) ? hist[t] : 0;
    if (t < 256) lps[t] = d;
    __syncthreads();
    for (int off = 1; off < 256; off <<= 1) {
        int val = (t >= off && t < 256) ? lps[t - off] : 0;
        __syncthreads();
        if (t < 256) lps[t] += val;
        __syncthreads();
    }
    int node = b * 256 + t;
    if (t < 256 && node < NN) {
        rowptr[node] = bstart + lps[t] - d;
        int db = d < 63 ? d : 63;
        int bkt = 63 - db;                   // descending degree (LPT)
        int lr2 = atomicAdd(&lh[bkt], 1);
        pr[node] = (lr2 << 6) | bkt;
    }
    if (b == 0 && t == 0) rowptr[NN] = NE;
    __syncthreads();
    if (t < 64) bhT[t * NBUCK + b] = lh[t];

    // pass 2: expand + moments (even/odd lane-pair split, shfl_xor exchange)
    float acc[39];
#pragma unroll
    for (int i = 0; i < 39; ++i) acc[i] = 0.0f;

    for (int j = bstart + t; (j - (t & 1)) < bend; j += 512) {
        bool valid = j < bend;
        float e[11];
        if (valid) {
            unsigned long long r = bucketed[j];
            int dl = (int)((r >> 47) & 255u);
            int s = (int)((r >> 30) & 0x1FFFFu);
            float a0 = (float)(unsigned)((r >> 15) & 0x7FFFu) * (1.0f / 32768.0f);
            float a1 = (float)(unsigned)(r & 0x7FFFu) * (1.0f / 32768.0f);
            int dn = b * 256 + dl;
            float4 s0 = *(const float4*)(v + (size_t)s * 8);
            float4 s1 = *(const float4*)(v + (size_t)s * 8 + 4);
            float4 d0 = *(const float4*)(v + (size_t)dn * 8);
            float4 d1 = *(const float4*)(v + (size_t)dn * 8 + 4);
            float df[8];
            df[0] = d0.x - s0.x; df[1] = d0.y - s0.y;
            df[2] = d0.z - s0.z; df[3] = d0.w - s0.w;
            df[4] = d1.x - s1.x; df[5] = d1.y - s1.y;
            df[6] = d1.z - s1.z; df[7] = d1.w - s1.w;
            float nsq = 0.0f;
#pragma unroll
            for (int q = 0; q < 8; ++q) nsq = fmaf(df[q], df[q], nsq);
            float nrm = sqrtf(nsq);
            float inv = __builtin_amdgcn_rcpf(nrm + EPS_NORM);
            e[0] = a0; e[1] = a1; e[2] = nrm;
#pragma unroll
            for (int q = 0; q < 8; ++q) e[3 + q] = df[q] * inv;

            int o = j - bstart;
            int lr = (o < 6144) ? (int)pos16[o] : 0;
            int pos = bstart + (lps[dl] - hist[dl]) + lr;
            uint4 lo;
            lo.x = pk2(e[0], e[1]); lo.y = pk2(e[2], e[3]);
            lo.z = pk2(e[4], e[5]); lo.w = pk2(e[6], e[7]);
            A16[pos] = lo;
            unsigned q10 = __float2uint_rn((e[10] + 1.0f) * 16383.5f);
            if (q10 > 32767u) q10 = 32767u;
            uint2 hv;
            hv.x = pk2(e[8], e[9]);
            hv.y = ((unsigned)s << 15) | q10;
            B8[pos] = hv;
        } else {
#pragma unroll
            for (int k = 0; k < 11; ++k) e[k] = 0.0f;
        }
        float eo[11];
#pragma unroll
        for (int k = 0; k < 11; ++k) eo[k] = __shfl_xor(e[k], 1);
        if (!(t & 1)) {
#pragma unroll
            for (int k = 0; k < 11; ++k) acc[k] += e[k] + eo[k];
            int p = 11;
#pragma unroll
            for (int k = 0; k < 11; ++k)
#pragma unroll
                for (int l = k; l < 11; ++l) {
                    if (p < 39) {
                        acc[p] = fmaf(e[k], e[l], acc[p]);
                        acc[p] = fmaf(eo[k], eo[l], acc[p]);
                    }
                    ++p;
                }
        } else {
            int p = 11;
#pragma unroll
            for (int k = 0; k < 11; ++k)
#pragma unroll
                for (int l = k; l < 11; ++l) {
                    if (p >= 39) {
                        acc[p - 39] = fmaf(e[k], e[l], acc[p - 39]);
                        acc[p - 39] = fmaf(eo[k], eo[l], acc[p - 39]);
                    }
                    ++p;
                }
        }
    }

    // parity-preserving butterfly: lane0 sums even lanes, lane1 odd lanes.
#pragma unroll
    for (int i = 0; i < 39; ++i) {
        float x = acc[i];
        x += __shfl_down(x, 2);
        x += __shfl_down(x, 4);
        x += __shfl_down(x, 8);
        x += __shfl_down(x, 16);
        x += __shfl_down(x, 32);
        acc[i] = x;
    }
    int wave = t >> 6;
    int lane = t & 63;
    if (lane == 0) {
#pragma unroll
        for (int i = 0; i < 39; ++i) lsum[wave][i] = acc[i];
    }
    if (lane == 1) {
#pragma unroll
        for (int i = 0; i < 38; ++i) lsum[wave][39 + i] = acc[i];
    }
    __syncthreads();
    if (t < 77) {
        float s = 0.0f;
#pragma unroll
        for (int w = 0; w < 8; ++w) s += lsum[w][t];
        partials[b * 77 + t] = s;
    }
}

// BN closed-form; fold scale into W'/b'; emit f16-pair packed weights (5 rows).
__global__ void bn_finalize_kernel(
    const float* __restrict__ partials,
    const float* __restrict__ w0, const float* __restrict__ b0,
    const float* __restrict__ g0, const float* __restrict__ be0,
    const float* __restrict__ w1, const float* __restrict__ b1,
    const float* __restrict__ g1, const float* __restrict__ be1,
    float* __restrict__ wbp)   // layer l at +l*1152: W'[704], b'[64], pk[320]
{
    __shared__ double gs[77];
    int t = threadIdx.x;
    if (t < 77) {
        double s = 0.0;
        for (int b = 0; b < NBUCK; ++b) s += (double)partials[b * 77 + t];
        gs[t] = s;
    }
    __syncthreads();
    if (t >= 128) return;
    int layer = t >> 6;
    int c = t & 63;
    const float* W  = layer ? w1 : w0;
    const float* B  = layer ? b1 : b0;
    const float* G  = layer ? g1 : g0;
    const float* BE = layer ? be1 : be0;

    const double invE = 1.0 / (double)NE;
    double m[11], wv[11];
    for (int k = 0; k < 11; ++k) {
        m[k] = gs[k] * invE;
        wv[k] = (double)W[k * 64 + c];
    }
    double md = 0.0;
    for (int k = 0; k < 11; ++k) md += m[k] * wv[k];
    double s2 = 0.0;
    int p = 11;
    for (int k = 0; k < 11; ++k)
        for (int l = k; l < 11; ++l) {
            double Me = gs[p] * invE; ++p;
            double term = Me * wv[k] * wv[l];
            s2 += (k == l) ? term : 2.0 * term;
        }
    double var = s2 - md * md;
    double mu = md + (double)B[c];
    float scale = (float)((double)G[c] / sqrt(var + (double)EPS_BN));
    float shift = (float)((double)BE[c] - mu * (double)scale);

    float* wpd = wbp + layer * 1152;
    for (int k = 0; k < 11; ++k) wpd[k * 64 + c] = W[k * 64 + c] * scale;
    wpd[704 + c] = fmaf(B[c], scale, shift);
    unsigned* pw = (unsigned*)(wpd + 768);
    for (int kp = 0; kp < 5; ++kp) {
        float wlo = W[(2 * kp) * 64 + c] * scale;
        float whi = W[(2 * kp + 1) * 64 + c] * scale;
        pw[kp * 64 + c] = pk2(wlo, whi);
    }
}

__global__ void __launch_bounds__(256) permB_kernel(
    const int* __restrict__ pr, const int* __restrict__ bhT,
    const int* __restrict__ rowptr, int4* __restrict__ perm4)
{
    int n = blockIdx.x * 256 + threadIdx.x;
    if (n >= NN) return;
    int p = pr[n];
    int bkt = p & 63, lrank = p >> 6, b = n >> 8;
    int pos = bhT[bkt * NBUCK + b] + lrank;
    perm4[pos] = make_int4(n, rowptr[n], rowptr[n + 1], 0);
}

// Edge body: e-pairs from A16/B8, packed f16 weights + f32 row 10.
#define FAT_BODY3(LO, HB, E10, XI)                                           \
    do {                                                                     \
        h2 ep0 = u2h((LO).x), ep1 = u2h((LO).y);                             \
        h2 ep2 = u2h((LO).z), ep3 = u2h((LO).w);                             \
        h2 ep4 = u2h((HB).x);                                                \
        _Pragma("unroll")                                                    \
        for (int o = 0; o < 8; ++o) {                                        \
            float hh = breg[o];                                              \
            hh = FDOT2(ep0, pw[0][o], hh);                                   \
            hh = FDOT2(ep1, pw[1][o], hh);                                   \
            hh = FDOT2(ep2, pw[2][o], hh);                                   \
            hh = FDOT2(ep3, pw[3][o], hh);                                   \
            hh = FDOT2(ep4, pw[4][o], hh);                                   \
            hh = fmaf((E10), w10[o], hh);                                    \
            msg[o] = fmaf((XI), fast_tanh(hh), msg[o]);                      \
        }                                                                    \
    } while (0)

// Per-layer fused gather-message + mean + root + lrelu (+residual).
template<int LAYER>
__global__ void __launch_bounds__(256)
__attribute__((amdgpu_waves_per_eu(2, 6))) layer_fat_kernel(
    const float* __restrict__ vres,
    const float* __restrict__ x,
    const uint4* __restrict__ A16, const uint2* __restrict__ B8,
    const int4* __restrict__ perm4,
    const float* __restrict__ wb,   // layer base: W'f32[704], b'[64], pk[320]
    const float* __restrict__ rw, const float* __restrict__ rb,
    float* __restrict__ out)
{
    int g = blockIdx.x * 256 + threadIdx.x;
    int4 pm = perm4[g >> 3];
    int n = pm.x, rp0 = pm.y, rp1 = pm.z;
    int i = g & 7;

    h2 pw[5][8];
    const unsigned* pwg = (const unsigned*)(wb + 768);
#pragma unroll
    for (int kp = 0; kp < 5; ++kp) {
        uint4 pa = *(const uint4*)(pwg + kp * 64 + i * 8);
        uint4 pb = *(const uint4*)(pwg + kp * 64 + i * 8 + 4);
        pw[kp][0] = u2h(pa.x); pw[kp][1] = u2h(pa.y);
        pw[kp][2] = u2h(pa.z); pw[kp][3] = u2h(pa.w);
        pw[kp][4] = u2h(pb.x); pw[kp][5] = u2h(pb.y);
        pw[kp][6] = u2h(pb.z); pw[kp][7] = u2h(pb.w);
    }
    float w10[8];
    {
        float4 wa = *(const float4*)(wb + 640 + i * 8);
        float4 wc = *(const float4*)(wb + 640 + i * 8 + 4);
        w10[0] = wa.x; w10[1] = wa.y; w10[2] = wa.z; w10[3] = wa.w;
        w10[4] = wc.x; w10[5] = wc.y; w10[6] = wc.z; w10[7] = wc.w;
    }
    float breg[8];
    {
        float4 ba = *(const float4*)(wb + 704 + i * 8);
        float4 bb = *(const float4*)(wb + 704 + i * 8 + 4);
        breg[0] = ba.x; breg[1] = ba.y; breg[2] = ba.z; breg[3] = ba.w;
        breg[4] = bb.x; breg[5] = bb.y; breg[6] = bb.z; breg[7] = bb.w;
    }

    float4 vd0 = *(const float4*)(vres + (size_t)n * 8);
    float4 vd1 = *(const float4*)(vres + (size_t)n * 8 + 4);
    float vd[8] = {vd0.x, vd0.y, vd0.z, vd0.w, vd1.x, vd1.y, vd1.z, vd1.w};

    float msg[8];
#pragma unroll
    for (int o = 0; o < 8; ++o) msg[o] = 0.0f;

    int j = rp0;
    for (; j + 2 <= rp1; j += 2) {
        uint4 lo0 = A16[j];
        uint4 lo1 = A16[j + 1];
        uint2 hb0 = B8[j];
        uint2 hb1 = B8[j + 1];
        int s0 = (int)(hb0.y >> 15);
        int s1 = (int)(hb1.y >> 15);
        float e10a = fmaf((float)(hb0.y & 0x7FFFu), 1.0f / 16383.5f, -1.0f);
        float e10b = fmaf((float)(hb1.y & 0x7FFFu), 1.0f / 16383.5f, -1.0f);
        float xi0 = x[(size_t)s0 * 8 + i];
        float xi1 = x[(size_t)s1 * 8 + i];
        FAT_BODY3(lo0, hb0, e10a, xi0);
        FAT_BODY3(lo1, hb1, e10b, xi1);
    }
    if (j < rp1) {
        uint4 lo0 = A16[j];
        uint2 hb0 = B8[j];
        int s0 = (int)(hb0.y >> 15);
        float e10a = fmaf((float)(hb0.y & 0x7FFFu), 1.0f / 16383.5f, -1.0f);
        float xi0 = x[(size_t)s0 * 8 + i];
        FAT_BODY3(lo0, hb0, e10a, xi0);
    }

#pragma unroll
    for (int o = 0; o < 8; ++o) {
        float m = msg[o];
        m += __shfl_xor(m, 1);
        m += __shfl_xor(m, 2);
        m += __shfl_xor(m, 4);
        msg[o] = m;
    }
    float mo = msg[0];
#pragma unroll
    for (int o = 1; o < 8; ++o) if (i == o) mo = msg[o];

    float cf = (float)(rp1 - rp0);
    float invc = __builtin_amdgcn_rcpf(fmaxf(cf, 1.0f));

    float xn[8];
    if (LAYER == 0) {
#pragma unroll
        for (int q = 0; q < 8; ++q) xn[q] = vd[q];
    } else {
        float4 x0 = *(const float4*)(x + (size_t)n * 8);
        float4 x1 = *(const float4*)(x + (size_t)n * 8 + 4);
        xn[0] = x0.x; xn[1] = x0.y; xn[2] = x0.z; xn[3] = x0.w;
        xn[4] = x1.x; xn[5] = x1.y; xn[6] = x1.z; xn[7] = x1.w;
    }
    float a = fmaf(mo, invc, rb[i]);
#pragma unroll
    for (int k = 0; k < 8; ++k) a = fmaf(xn[k], rw[k * 8 + i], a);
    float y = (a > 0.0f) ? a : SLOPE * a;
    if (LAYER == 1) y += vres[(size_t)n * 8 + i];
    out[(size_t)n * 8 + i] = y;
}

extern "C" void kernel_launch(void* const* d_in, const int* in_sizes, int n_in,
                              void* d_out, int out_size, void* d_ws, size_t ws_size,
                              hipStream_t stream) {
    const float* v  = (const float*)d_in[0];
    const int* ei   = (const int*)d_in[1];
    const float* ea = (const float*)d_in[2];
    const float* en_w0  = (const float*)d_in[3];
    const float* en_b0  = (const float*)d_in[4];
    const float* en_g0  = (const float*)d_in[5];
    const float* en_be0 = (const float*)d_in[6];
    const float* rw0    = (const float*)d_in[7];
    const float* rb0    = (const float*)d_in[8];
    const float* en_w1  = (const float*)d_in[9];
    const float* en_b1  = (const float*)d_in[10];
    const float* en_g1  = (const float*)d_in[11];
    const float* en_be1 = (const float*)d_in[12];
    const float* rw1    = (const float*)d_in[13];
    const float* rb1    = (const float*)d_in[14];

    char* ws = (char*)d_ws;
    float* partials = (float*)(ws);                    // 391*77*4 = 120,428 B
    float* wbp      = (float*)(ws + 131072);           // 9,216 B
    int*   rowptr   = (int*)  (ws + 143360);           // 400,004 B
    int*   pr       = (int*)  (ws + 543744);           // 400,000 B
    int4*  perm4    = (int4*) (ws + 944128);           // 1,600,000 B
    int*   bhT      = (int*)  (ws + 2544128);          // 100,096 B
    int*   gbsum    = (int*)  (ws + 2644224);          // 392 B
    int*   cbsum    = (int*)  (ws + 2644736);          // 2,392 B
    int*   cntT     = (int*)  (ws + 2648064);          // 611,524 B -> 3,259,588
    float* v1       = (float*)(ws + 3259904);          // 3,200,000 B -> 6,459,904
    unsigned long long* bucketed = (unsigned long long*)(ws + 6460416); // 12.8 MB -> 19,260,416
    uint4* A16      = (uint4*)(ws + 19260416);         // 25.6 MB -> 44,860,416
    uint2* B8       = (uint2*)(ws + 44860416);         // 12.8 MB -> 57,660,416
    float* vout     = (float*)d_out;

    r1_count_kernel<<<NBLK, 256, 0, stream>>>(ei, cntT);
    gscanA_kernel<<<CSB, 256, 0, stream>>>(cntT, cbsum, CNT_LEN);
    gscanB_kernel<<<CSB, 256, 0, stream>>>(cntT, cbsum, CNT_LEN);
    r2_scatter_kernel<<<NBLK, 256, 0, stream>>>(ei, ea, cntT, bucketed);
    finalize_kernel<<<NBUCK, 512, 0, stream>>>(bucketed, cntT, v, A16, B8,
                                               rowptr, pr, bhT, partials);
    gscanA_kernel<<<GS_BLOCKS, 256, 0, stream>>>(bhT, gbsum, GS_LEN);
    gscanB_kernel<<<GS_BLOCKS, 256, 0, stream>>>(bhT, gbsum, GS_LEN);
    permB_kernel<<<NBUCK, 256, 0, stream>>>(pr, bhT, rowptr, perm4);
    bn_finalize_kernel<<<1, 128, 0, stream>>>(partials, en_w0, en_b0, en_g0, en_be0,
                                              en_w1, en_b1, en_g1, en_be1, wbp);

    const int LB = (NN * 8) / 256;   // 3125, exact
    layer_fat_kernel<0><<<LB, 256, 0, stream>>>(v, v,  A16, B8, perm4, wbp,        rw0, rb0, v1);
    layer_fat_kernel<1><<<LB, 256, 0, stream>>>(v, v1, A16, B8, perm4, wbp + 1152, rw1, rb1, vout);
}

// Round 19
// 202.587 us; speedup vs baseline: 1.1138x; 1.0689x over previous
//
#include <hip/hip_runtime.h>
#include <hip/hip_fp16.h>
#include <math.h>

#define NN 100000
#define NE 1600000
#define EPS_BN 1e-5f
#define EPS_NORM 1e-12f
#define SLOPE 0.01f
#define NBUCK 391                            // = ceil(NN/256); bucket = dst>>8
#define NBLK 391                             // edge-chunk blocks (4096 edges each)
#define EPB 4096                             // edges per r1/r2 block
#define CNT_LEN (NBUCK * NBLK)               // 152,881
#define CSB ((CNT_LEN + 255) / 256)          // 598
#define GS_LEN (64 * NBUCK)                  // 25024
#define GS_BLOCKS ((GS_LEN + 255) / 256)     // 98
#define MAXB 6144                            // max edges/bucket (Poisson(4096)+slack)

typedef _Float16 h2 __attribute__((ext_vector_type(2)));

#if __has_builtin(__builtin_amdgcn_exp2f)
#define EXP2F(x) __builtin_amdgcn_exp2f(x)
#else
#define EXP2F(x) exp2f(x)
#endif

__device__ __forceinline__ float fast_tanh(float x) {
    float t = EXP2F(x * 2.885390082f);
    return fmaf(-2.0f, __builtin_amdgcn_rcpf(t + 1.0f), 1.0f);
}

__device__ __forceinline__ unsigned pk2(float a, float b) {
    union { __half2 h; unsigned u; } c;
    c.h = __float22half2_rn(make_float2(a, b));
    return c.u;
}

__device__ __forceinline__ h2 u2h(unsigned x) {
    union { unsigned u; h2 h; } c; c.u = x; return c.h;
}

#if __has_builtin(__builtin_amdgcn_fdot2)
#define FDOT2(A, B, C) __builtin_amdgcn_fdot2((A), (B), (C), false)
#else
__device__ __forceinline__ float FDOT2(h2 a, h2 b, float c) {
    return fmaf((float)a.x, (float)b.x, fmaf((float)a.y, (float)b.y, c));
}
#endif

// R1: per-block LDS bucket histogram over 4096 edges (bucket = dst>>8).
__global__ void __launch_bounds__(256) r1_count_kernel(
    const int* __restrict__ ei, int* __restrict__ cntT)
{
    __shared__ int h[NBUCK];
    int b = blockIdx.x, t = threadIdx.x;
    for (int j = t; j < NBUCK; j += 256) h[j] = 0;
    __syncthreads();
#pragma unroll
    for (int it = 0; it < 4; ++it) {
        int e4 = b * EPB + it * 1024 + t * 4;
        if (e4 < NE) {
            int4 d4 = *(const int4*)(ei + NE + e4);
            atomicAdd(&h[d4.x >> 8], 1);
            atomicAdd(&h[d4.y >> 8], 1);
            atomicAdd(&h[d4.z >> 8], 1);
            atomicAdd(&h[d4.w >> 8], 1);
        }
    }
    __syncthreads();
    for (int j = t; j < NBUCK; j += 256) cntT[(size_t)j * NBLK + b] = h[j];
}

// Generic 2-level exclusive scan (block pass + offset pass), length-param'd.
__global__ void __launch_bounds__(256) gscanA_kernel(
    int* __restrict__ a, int* __restrict__ bs, int len)
{
    int b = blockIdx.x, t = threadIdx.x;
    int i = b * 256 + t;
    int d = (i < len) ? a[i] : 0;
    __shared__ int sh[256];
    sh[t] = d;
    __syncthreads();
    for (int off = 1; off < 256; off <<= 1) {
        int val = (t >= off) ? sh[t - off] : 0;
        __syncthreads();
        sh[t] += val;
        __syncthreads();
    }
    if (i < len) a[i] = sh[t] - d;
    if (t == 255) bs[b] = sh[255];
}

__global__ void __launch_bounds__(256) gscanB_kernel(
    int* __restrict__ a, const int* __restrict__ bs, int len)
{
    int b = blockIdx.x, t = threadIdx.x;
    __shared__ int sh[256];
    int s = 0;
    for (int j = t; j < b; j += 256) s += bs[j];
    sh[t] = s;
    __syncthreads();
    for (int off = 128; off > 0; off >>= 1) {
        if (t < off) sh[t] += sh[t + off];
        __syncthreads();
    }
    int boff = sh[0];
    int i = b * 256 + t;
    if (i < len) a[i] += boff;
}

// R2: bucket-scatter packed recs [dst:17|src:17|a0:15|a1:15] via LDS ranks.
__global__ void __launch_bounds__(256) r2_scatter_kernel(
    const int* __restrict__ ei, const float* __restrict__ ea,
    const int* __restrict__ cntT, unsigned long long* __restrict__ bucketed)
{
    __shared__ int h[NBUCK];
    __shared__ int base[NBUCK];
    int b = blockIdx.x, t = threadIdx.x;
    for (int j = t; j < NBUCK; j += 256) {
        h[j] = 0;
        base[j] = cntT[(size_t)j * NBLK + b];
    }
    __syncthreads();
#pragma unroll
    for (int it = 0; it < 4; ++it) {
        int e4 = b * EPB + it * 1024 + t * 4;
        if (e4 < NE) {
            int4 s4 = *(const int4*)(ei + e4);
            int4 d4 = *(const int4*)(ei + NE + e4);
            float4 a01 = *(const float4*)(ea + 2 * (size_t)e4);
            float4 a23 = *(const float4*)(ea + 2 * (size_t)e4 + 4);
#define DO_EDGE(S, D, A0, A1)                                                \
            {                                                                \
                unsigned a0q = __float2uint_rn((A0) * 32768.0f);             \
                if (a0q > 32767u) a0q = 32767u;                              \
                unsigned a1q = __float2uint_rn((A1) * 32768.0f);             \
                if (a1q > 32767u) a1q = 32767u;                              \
                unsigned long long rec =                                     \
                      (((unsigned long long)(unsigned)(D)) << 47)            \
                    | (((unsigned long long)(unsigned)(S)) << 30)            \
                    | (((unsigned long long)a0q) << 15)                      \
                    | ((unsigned long long)a1q);                             \
                int bb = (D) >> 8;                                           \
                int lr = atomicAdd(&h[bb], 1);                               \
                bucketed[base[bb] + lr] = rec;                               \
            }
            DO_EDGE(s4.x, d4.x, a01.x, a01.y)
            DO_EDGE(s4.y, d4.y, a01.z, a01.w)
            DO_EDGE(s4.z, d4.z, a23.x, a23.y)
            DO_EDGE(s4.w, d4.w, a23.z, a23.w)
#undef DO_EDGE
        }
    }
}

// R3 FUSED: per-bucket finalize + expand + moments. 512 threads/bucket.
// r18 lesson: the scattered A16/B8 stores (bucketed order -> sorted pos)
// caused 2.4x write amplification (93MB vs 39MB payload). Fix: build the
// INVERSE permutation in LDS, iterate final positions, write COALESCED;
// the random accesses become L2-hot reads of bucketed (reads don't amplify).
__global__ void __launch_bounds__(512)
__attribute__((amdgpu_waves_per_eu(2, 4))) finalize_kernel(
    const unsigned long long* __restrict__ bucketed,
    const int* __restrict__ cntT,
    const float* __restrict__ v,
    uint4* __restrict__ A16, uint2* __restrict__ B8,
    int* __restrict__ rowptr, int* __restrict__ pr, int* __restrict__ bhT,
    float* __restrict__ partials)   // [NBUCK][77]
{
    __shared__ int hist[256], lps[256], lh[64];
    __shared__ unsigned short pos16[MAXB];
    __shared__ unsigned char dl8[MAXB];
    __shared__ unsigned short inv16[MAXB];
    __shared__ float lsum[8][77];
    int b = blockIdx.x, t = threadIdx.x;
    if (t < 256) hist[t] = 0;
    if (t < 64) lh[t] = 0;
    __syncthreads();
    int bstart = cntT[(size_t)b * NBLK];
    int bend = (b == NBUCK - 1) ? NE : cntT[(size_t)(b + 1) * NBLK];
    int bsize = bend - bstart;

    for (int o = t; o < bsize; o += 512) {
        unsigned long long r = bucketed[bstart + o];
        int dl = (int)((r >> 47) & 255u);
        int lr = atomicAdd(&hist[dl], 1);
        pos16[o] = (unsigned short)lr;
        dl8[o] = (unsigned char)dl;
    }
    __syncthreads();
    int d = (t < 256) ? hist[t] : 0;
    if (t < 256) lps[t] = d;
    __syncthreads();
    for (int off = 1; off < 256; off <<= 1) {
        int val = (t >= off && t < 256) ? lps[t - off] : 0;
        __syncthreads();
        if (t < 256) lps[t] += val;
        __syncthreads();
    }
    int node = b * 256 + t;
    if (t < 256 && node < NN) {
        rowptr[node] = bstart + lps[t] - d;
        int db = d < 63 ? d : 63;
        int bkt = 63 - db;                   // descending degree (LPT)
        int lr2 = atomicAdd(&lh[bkt], 1);
        pr[node] = (lr2 << 6) | bkt;
    }
    if (b == 0 && t == 0) rowptr[NN] = NE;
    __syncthreads();
    if (t < 64) bhT[t * NBUCK + b] = lh[t];

    // invert the permutation: inv16[final_local_pos] = source offset
    for (int o = t; o < bsize; o += 512) {
        int dl = (int)dl8[o];
        int fp = (lps[dl] - hist[dl]) + (int)pos16[o];
        inv16[fp] = (unsigned short)o;
    }
    __syncthreads();

    // pass 2: iterate FINAL positions (coalesced writes), expand + moments
    float acc[39];
#pragma unroll
    for (int i = 0; i < 39; ++i) acc[i] = 0.0f;

    for (int p = t; (p - (t & 1)) < bsize; p += 512) {
        bool valid = p < bsize;
        float e[11];
        if (valid) {
            int o = (int)inv16[p];
            unsigned long long r = bucketed[bstart + o];   // L2-hot random read
            int dl = (int)((r >> 47) & 255u);
            int s = (int)((r >> 30) & 0x1FFFFu);
            float a0 = (float)(unsigned)((r >> 15) & 0x7FFFu) * (1.0f / 32768.0f);
            float a1 = (float)(unsigned)(r & 0x7FFFu) * (1.0f / 32768.0f);
            int dn = b * 256 + dl;
            float4 s0 = *(const float4*)(v + (size_t)s * 8);
            float4 s1 = *(const float4*)(v + (size_t)s * 8 + 4);
            float4 d0 = *(const float4*)(v + (size_t)dn * 8);
            float4 d1 = *(const float4*)(v + (size_t)dn * 8 + 4);
            float df[8];
            df[0] = d0.x - s0.x; df[1] = d0.y - s0.y;
            df[2] = d0.z - s0.z; df[3] = d0.w - s0.w;
            df[4] = d1.x - s1.x; df[5] = d1.y - s1.y;
            df[6] = d1.z - s1.z; df[7] = d1.w - s1.w;
            float nsq = 0.0f;
#pragma unroll
            for (int q = 0; q < 8; ++q) nsq = fmaf(df[q], df[q], nsq);
            float nrm = sqrtf(nsq);
            float inv = __builtin_amdgcn_rcpf(nrm + EPS_NORM);
            e[0] = a0; e[1] = a1; e[2] = nrm;
#pragma unroll
            for (int q = 0; q < 8; ++q) e[3 + q] = df[q] * inv;

            uint4 lo;
            lo.x = pk2(e[0], e[1]); lo.y = pk2(e[2], e[3]);
            lo.z = pk2(e[4], e[5]); lo.w = pk2(e[6], e[7]);
            A16[bstart + p] = lo;                     // coalesced
            unsigned q10 = __float2uint_rn((e[10] + 1.0f) * 16383.5f);
            if (q10 > 32767u) q10 = 32767u;
            uint2 hv;
            hv.x = pk2(e[8], e[9]);
            hv.y = ((unsigned)s << 15) | q10;
            B8[bstart + p] = hv;                      // coalesced
        } else {
#pragma unroll
            for (int k = 0; k < 11; ++k) e[k] = 0.0f;
        }
        float eo[11];
#pragma unroll
        for (int k = 0; k < 11; ++k) eo[k] = __shfl_xor(e[k], 1);
        if (!(t & 1)) {
#pragma unroll
            for (int k = 0; k < 11; ++k) acc[k] += e[k] + eo[k];
            int p2 = 11;
#pragma unroll
            for (int k = 0; k < 11; ++k)
#pragma unroll
                for (int l = k; l < 11; ++l) {
                    if (p2 < 39) {
                        acc[p2] = fmaf(e[k], e[l], acc[p2]);
                        acc[p2] = fmaf(eo[k], eo[l], acc[p2]);
                    }
                    ++p2;
                }
        } else {
            int p2 = 11;
#pragma unroll
            for (int k = 0; k < 11; ++k)
#pragma unroll
                for (int l = k; l < 11; ++l) {
                    if (p2 >= 39) {
                        acc[p2 - 39] = fmaf(e[k], e[l], acc[p2 - 39]);
                        acc[p2 - 39] = fmaf(eo[k], eo[l], acc[p2 - 39]);
                    }
                    ++p2;
                }
        }
    }

    // parity-preserving butterfly: lane0 sums even lanes, lane1 odd lanes.
#pragma unroll
    for (int i = 0; i < 39; ++i) {
        float x = acc[i];
        x += __shfl_down(x, 2);
        x += __shfl_down(x, 4);
        x += __shfl_down(x, 8);
        x += __shfl_down(x, 16);
        x += __shfl_down(x, 32);
        acc[i] = x;
    }
    int wave = t >> 6;
    int lane = t & 63;
    if (lane == 0) {
#pragma unroll
        for (int i = 0; i < 39; ++i) lsum[wave][i] = acc[i];
    }
    if (lane == 1) {
#pragma unroll
        for (int i = 0; i < 38; ++i) lsum[wave][39 + i] = acc[i];
    }
    __syncthreads();
    if (t < 77) {
        float s = 0.0f;
#pragma unroll
        for (int w = 0; w < 8; ++w) s += lsum[w][t];
        partials[b * 77 + t] = s;
    }
}

// BN closed-form; fold scale into W'/b'; emit f16-pair packed weights (5 rows).
__global__ void bn_finalize_kernel(
    const float* __restrict__ partials,
    const float* __restrict__ w0, const float* __restrict__ b0,
    const float* __restrict__ g0, const float* __restrict__ be0,
    const float* __restrict__ w1, const float* __restrict__ b1,
    const float* __restrict__ g1, const float* __restrict__ be1,
    float* __restrict__ wbp)   // layer l at +l*1152: W'[704], b'[64], pk[320]
{
    __shared__ double gs[77];
    int t = threadIdx.x;
    if (t < 77) {
        double s = 0.0;
        for (int b = 0; b < NBUCK; ++b) s += (double)partials[b * 77 + t];
        gs[t] = s;
    }
    __syncthreads();
    if (t >= 128) return;
    int layer = t >> 6;
    int c = t & 63;
    const float* W  = layer ? w1 : w0;
    const float* B  = layer ? b1 : b0;
    const float* G  = layer ? g1 : g0;
    const float* BE = layer ? be1 : be0;

    const double invE = 1.0 / (double)NE;
    double m[11], wv[11];
    for (int k = 0; k < 11; ++k) {
        m[k] = gs[k] * invE;
        wv[k] = (double)W[k * 64 + c];
    }
    double md = 0.0;
    for (int k = 0; k < 11; ++k) md += m[k] * wv[k];
    double s2 = 0.0;
    int p = 11;
    for (int k = 0; k < 11; ++k)
        for (int l = k; l < 11; ++l) {
            double Me = gs[p] * invE; ++p;
            double term = Me * wv[k] * wv[l];
            s2 += (k == l) ? term : 2.0 * term;
        }
    double var = s2 - md * md;
    double mu = md + (double)B[c];
    float scale = (float)((double)G[c] / sqrt(var + (double)EPS_BN));
    float shift = (float)((double)BE[c] - mu * (double)scale);

    float* wpd = wbp + layer * 1152;
    for (int k = 0; k < 11; ++k) wpd[k * 64 + c] = W[k * 64 + c] * scale;
    wpd[704 + c] = fmaf(B[c], scale, shift);
    unsigned* pw = (unsigned*)(wpd + 768);
    for (int kp = 0; kp < 5; ++kp) {
        float wlo = W[(2 * kp) * 64 + c] * scale;
        float whi = W[(2 * kp + 1) * 64 + c] * scale;
        pw[kp * 64 + c] = pk2(wlo, whi);
    }
}

__global__ void __launch_bounds__(256) permB_kernel(
    const int* __restrict__ pr, const int* __restrict__ bhT,
    const int* __restrict__ rowptr, int4* __restrict__ perm4)
{
    int n = blockIdx.x * 256 + threadIdx.x;
    if (n >= NN) return;
    int p = pr[n];
    int bkt = p & 63, lrank = p >> 6, b = n >> 8;
    int pos = bhT[bkt * NBUCK + b] + lrank;
    perm4[pos] = make_int4(n, rowptr[n], rowptr[n + 1], 0);
}

// Edge body: e-pairs from A16/B8, packed f16 weights + f32 row 10.
#define FAT_BODY3(LO, HB, E10, XI)                                           \
    do {                                                                     \
        h2 ep0 = u2h((LO).x), ep1 = u2h((LO).y);                             \
        h2 ep2 = u2h((LO).z), ep3 = u2h((LO).w);                             \
        h2 ep4 = u2h((HB).x);                                                \
        _Pragma("unroll")                                                    \
        for (int o = 0; o < 8; ++o) {                                        \
            float hh = breg[o];                                              \
            hh = FDOT2(ep0, pw[0][o], hh);                                   \
            hh = FDOT2(ep1, pw[1][o], hh);                                   \
            hh = FDOT2(ep2, pw[2][o], hh);                                   \
            hh = FDOT2(ep3, pw[3][o], hh);                                   \
            hh = FDOT2(ep4, pw[4][o], hh);                                   \
            hh = fmaf((E10), w10[o], hh);                                    \
            msg[o] = fmaf((XI), fast_tanh(hh), msg[o]);                      \
        }                                                                    \
    } while (0)

// Per-layer fused gather-message + mean + root + lrelu (+residual).
template<int LAYER>
__global__ void __launch_bounds__(256)
__attribute__((amdgpu_waves_per_eu(2, 6))) layer_fat_kernel(
    const float* __restrict__ vres,
    const float* __restrict__ x,
    const uint4* __restrict__ A16, const uint2* __restrict__ B8,
    const int4* __restrict__ perm4,
    const float* __restrict__ wb,   // layer base: W'f32[704], b'[64], pk[320]
    const float* __restrict__ rw, const float* __restrict__ rb,
    float* __restrict__ out)
{
    int g = blockIdx.x * 256 + threadIdx.x;
    int4 pm = perm4[g >> 3];
    int n = pm.x, rp0 = pm.y, rp1 = pm.z;
    int i = g & 7;

    h2 pw[5][8];
    const unsigned* pwg = (const unsigned*)(wb + 768);
#pragma unroll
    for (int kp = 0; kp < 5; ++kp) {
        uint4 pa = *(const uint4*)(pwg + kp * 64 + i * 8);
        uint4 pb = *(const uint4*)(pwg + kp * 64 + i * 8 + 4);
        pw[kp][0] = u2h(pa.x); pw[kp][1] = u2h(pa.y);
        pw[kp][2] = u2h(pa.z); pw[kp][3] = u2h(pa.w);
        pw[kp][4] = u2h(pb.x); pw[kp][5] = u2h(pb.y);
        pw[kp][6] = u2h(pb.z); pw[kp][7] = u2h(pb.w);
    }
    float w10[8];
    {
        float4 wa = *(const float4*)(wb + 640 + i * 8);
        float4 wc = *(const float4*)(wb + 640 + i * 8 + 4);
        w10[0] = wa.x; w10[1] = wa.y; w10[2] = wa.z; w10[3] = wa.w;
        w10[4] = wc.x; w10[5] = wc.y; w10[6] = wc.z; w10[7] = wc.w;
    }
    float breg[8];
    {
        float4 ba = *(const float4*)(wb + 704 + i * 8);
        float4 bb = *(const float4*)(wb + 704 + i * 8 + 4);
        breg[0] = ba.x; breg[1] = ba.y; breg[2] = ba.z; breg[3] = ba.w;
        breg[4] = bb.x; breg[5] = bb.y; breg[6] = bb.z; breg[7] = bb.w;
    }

    float4 vd0 = *(const float4*)(vres + (size_t)n * 8);
    float4 vd1 = *(const float4*)(vres + (size_t)n * 8 + 4);
    float vd[8] = {vd0.x, vd0.y, vd0.z, vd0.w, vd1.x, vd1.y, vd1.z, vd1.w};

    float msg[8];
#pragma unroll
    for (int o = 0; o < 8; ++o) msg[o] = 0.0f;

    int j = rp0;
    for (; j + 2 <= rp1; j += 2) {
        uint4 lo0 = A16[j];
        uint4 lo1 = A16[j + 1];
        uint2 hb0 = B8[j];
        uint2 hb1 = B8[j + 1];
        int s0 = (int)(hb0.y >> 15);
        int s1 = (int)(hb1.y >> 15);
        float e10a = fmaf((float)(hb0.y & 0x7FFFu), 1.0f / 16383.5f, -1.0f);
        float e10b = fmaf((float)(hb1.y & 0x7FFFu), 1.0f / 16383.5f, -1.0f);
        float xi0 = x[(size_t)s0 * 8 + i];
        float xi1 = x[(size_t)s1 * 8 + i];
        FAT_BODY3(lo0, hb0, e10a, xi0);
        FAT_BODY3(lo1, hb1, e10b, xi1);
    }
    if (j < rp1) {
        uint4 lo0 = A16[j];
        uint2 hb0 = B8[j];
        int s0 = (int)(hb0.y >> 15);
        float e10a = fmaf((float)(hb0.y & 0x7FFFu), 1.0f / 16383.5f, -1.0f);
        float xi0 = x[(size_t)s0 * 8 + i];
        FAT_BODY3(lo0, hb0, e10a, xi0);
    }

#pragma unroll
    for (int o = 0; o < 8; ++o) {
        float m = msg[o];
        m += __shfl_xor(m, 1);
        m += __shfl_xor(m, 2);
        m += __shfl_xor(m, 4);
        msg[o] = m;
    }
    float mo = msg[0];
#pragma unroll
    for (int o = 1; o < 8; ++o) if (i == o) mo = msg[o];

    float cf = (float)(rp1 - rp0);
    float invc = __builtin_amdgcn_rcpf(fmaxf(cf, 1.0f));

    float xn[8];
    if (LAYER == 0) {
#pragma unroll
        for (int q = 0; q < 8; ++q) xn[q] = vd[q];
    } else {
        float4 x0 = *(const float4*)(x + (size_t)n * 8);
        float4 x1 = *(const float4*)(x + (size_t)n * 8 + 4);
        xn[0] = x0.x; xn[1] = x0.y; xn[2] = x0.z; xn[3] = x0.w;
        xn[4] = x1.x; xn[5] = x1.y; xn[6] = x1.z; xn[7] = x1.w;
    }
    float a = fmaf(mo, invc, rb[i]);
#pragma unroll
    for (int k = 0; k < 8; ++k) a = fmaf(xn[k], rw[k * 8 + i], a);
    float y = (a > 0.0f) ? a : SLOPE * a;
    if (LAYER == 1) y += vres[(size_t)n * 8 + i];
    out[(size_t)n * 8 + i] = y;
}

extern "C" void kernel_launch(void* const* d_in, const int* in_sizes, int n_in,
                              void* d_out, int out_size, void* d_ws, size_t ws_size,
                              hipStream_t stream) {
    const float* v  = (const float*)d_in[0];
    const int* ei   = (const int*)d_in[1];
    const float* ea = (const float*)d_in[2];
    const float* en_w0  = (const float*)d_in[3];
    const float* en_b0  = (const float*)d_in[4];
    const float* en_g0  = (const float*)d_in[5];
    const float* en_be0 = (const float*)d_in[6];
    const float* rw0    = (const float*)d_in[7];
    const float* rb0    = (const float*)d_in[8];
    const float* en_w1  = (const float*)d_in[9];
    const float* en_b1  = (const float*)d_in[10];
    const float* en_g1  = (const float*)d_in[11];
    const float* en_be1 = (const float*)d_in[12];
    const float* rw1    = (const float*)d_in[13];
    const float* rb1    = (const float*)d_in[14];

    char* ws = (char*)d_ws;
    float* partials = (float*)(ws);                    // 120,428 B
    float* wbp      = (float*)(ws + 131072);           // 9,216 B
    int*   rowptr   = (int*)  (ws + 143360);           // 400,004 B
    int*   pr       = (int*)  (ws + 543744);           // 400,000 B
    int4*  perm4    = (int4*) (ws + 944128);           // 1,600,000 B
    int*   bhT      = (int*)  (ws + 2544128);          // 100,096 B
    int*   gbsum    = (int*)  (ws + 2644224);          // 392 B
    int*   cbsum    = (int*)  (ws + 2644736);          // 2,392 B
    int*   cntT     = (int*)  (ws + 2648064);          // 611,524 B
    float* v1       = (float*)(ws + 3259904);          // 3,200,000 B
    unsigned long long* bucketed = (unsigned long long*)(ws + 6460416); // 12.8 MB
    uint4* A16      = (uint4*)(ws + 19260416);         // 25.6 MB
    uint2* B8       = (uint2*)(ws + 44860416);         // 12.8 MB -> 57,660,416
    float* vout     = (float*)d_out;

    r1_count_kernel<<<NBLK, 256, 0, stream>>>(ei, cntT);
    gscanA_kernel<<<CSB, 256, 0, stream>>>(cntT, cbsum, CNT_LEN);
    gscanB_kernel<<<CSB, 256, 0, stream>>>(cntT, cbsum, CNT_LEN);
    r2_scatter_kernel<<<NBLK, 256, 0, stream>>>(ei, ea, cntT, bucketed);
    finalize_kernel<<<NBUCK, 512, 0, stream>>>(bucketed, cntT, v, A16, B8,
                                               rowptr, pr, bhT, partials);
    gscanA_kernel<<<GS_BLOCKS, 256, 0, stream>>>(bhT, gbsum, GS_LEN);
    gscanB_kernel<<<GS_BLOCKS, 256, 0, stream>>>(bhT, gbsum, GS_LEN);
    permB_kernel<<<NBUCK, 256, 0, stream>>>(pr, bhT, rowptr, perm4);
    bn_finalize_kernel<<<1, 128, 0, stream>>>(partials, en_w0, en_b0, en_g0, en_be0,
                                              en_w1, en_b1, en_g1, en_be1, wbp);

    const int LB = (NN * 8) / 256;   // 3125, exact
    layer_fat_kernel<0><<<LB, 256, 0, stream>>>(v, v,  A16, B8, perm4, wbp,        rw0, rb0, v1);
    layer_fat_kernel<1><<<LB, 256, 0, stream>>>(v, v1, A16, B8, perm4, wbp + 1152, rw1, rb1, vout);
}

// Round 20
// 201.698 us; speedup vs baseline: 1.1187x; 1.0044x over previous
//
#include <hip/hip_runtime.h>
#include <hip/hip_fp16.h>
#include <math.h>

#define NN 100000
#define NE 1600000
#define EPS_BN 1e-5f
#define EPS_NORM 1e-12f
#define SLOPE 0.01f
#define NBUCK 391                            // = ceil(NN/256); bucket = dst>>8
#define NBLK 391                             // edge-chunk blocks (4096 edges each)
#define EPB 4096                             // edges per r1/r2 block
#define CNT_LEN (NBUCK * NBLK)               // 152,881
#define CSB ((CNT_LEN + 255) / 256)          // 598
#define GS_LEN (64 * NBUCK)                  // 25024
#define GS_BLOCKS ((GS_LEN + 255) / 256)     // 98
#define MAXB 6144                            // max edges/bucket (Poisson(4096)+slack)

typedef _Float16 h2 __attribute__((ext_vector_type(2)));

#if __has_builtin(__builtin_amdgcn_exp2f)
#define EXP2F(x) __builtin_amdgcn_exp2f(x)
#else
#define EXP2F(x) exp2f(x)
#endif

__device__ __forceinline__ float fast_tanh(float x) {
    float t = EXP2F(x * 2.885390082f);
    return fmaf(-2.0f, __builtin_amdgcn_rcpf(t + 1.0f), 1.0f);
}

__device__ __forceinline__ unsigned pk2(float a, float b) {
    union { __half2 h; unsigned u; } c;
    c.h = __float22half2_rn(make_float2(a, b));
    return c.u;
}

// dot2 on u32-packed f16 pairs: builtin if available, else raw
// v_dot2_f32_f16 (present on CDNA; r19 theory: the scalar fallback may have
// been silently live, 6 ops per dot -> the 2.8x VALU gap in layer kernels).
#if __has_builtin(__builtin_amdgcn_fdot2)
__device__ __forceinline__ float fdot2u(unsigned a, unsigned b, float c) {
    union { unsigned u; h2 h; } ca, cb;
    ca.u = a; cb.u = b;
    return __builtin_amdgcn_fdot2(ca.h, cb.h, c, false);
}
#else
__device__ __forceinline__ float fdot2u(unsigned a, unsigned b, float c) {
    float d;
    asm("v_dot2_f32_f16 %0, %1, %2, %3" : "=v"(d) : "v"(a), "v"(b), "v"(c));
    return d;
}
#endif

// R1: per-block LDS bucket histogram over 4096 edges (bucket = dst>>8).
__global__ void __launch_bounds__(256) r1_count_kernel(
    const int* __restrict__ ei, int* __restrict__ cntT)
{
    __shared__ int h[NBUCK];
    int b = blockIdx.x, t = threadIdx.x;
    for (int j = t; j < NBUCK; j += 256) h[j] = 0;
    __syncthreads();
#pragma unroll
    for (int it = 0; it < 4; ++it) {
        int e4 = b * EPB + it * 1024 + t * 4;
        if (e4 < NE) {
            int4 d4 = *(const int4*)(ei + NE + e4);
            atomicAdd(&h[d4.x >> 8], 1);
            atomicAdd(&h[d4.y >> 8], 1);
            atomicAdd(&h[d4.z >> 8], 1);
            atomicAdd(&h[d4.w >> 8], 1);
        }
    }
    __syncthreads();
    for (int j = t; j < NBUCK; j += 256) cntT[(size_t)j * NBLK + b] = h[j];
}

// Generic 2-level exclusive scan (block pass + offset pass), length-param'd.
__global__ void __launch_bounds__(256) gscanA_kernel(
    int* __restrict__ a, int* __restrict__ bs, int len)
{
    int b = blockIdx.x, t = threadIdx.x;
    int i = b * 256 + t;
    int d = (i < len) ? a[i] : 0;
    __shared__ int sh[256];
    sh[t] = d;
    __syncthreads();
    for (int off = 1; off < 256; off <<= 1) {
        int val = (t >= off) ? sh[t - off] : 0;
        __syncthreads();
        sh[t] += val;
        __syncthreads();
    }
    if (i < len) a[i] = sh[t] - d;
    if (t == 255) bs[b] = sh[255];
}

__global__ void __launch_bounds__(256) gscanB_kernel(
    int* __restrict__ a, const int* __restrict__ bs, int len)
{
    int b = blockIdx.x, t = threadIdx.x;
    __shared__ int sh[256];
    int s = 0;
    for (int j = t; j < b; j += 256) s += bs[j];
    sh[t] = s;
    __syncthreads();
    for (int off = 128; off > 0; off >>= 1) {
        if (t < off) sh[t] += sh[t + off];
        __syncthreads();
    }
    int boff = sh[0];
    int i = b * 256 + t;
    if (i < len) a[i] += boff;
}

// R2: bucket-scatter packed recs [dst:17|src:17|a0:15|a1:15] via LDS ranks.
__global__ void __launch_bounds__(256) r2_scatter_kernel(
    const int* __restrict__ ei, const float* __restrict__ ea,
    const int* __restrict__ cntT, unsigned long long* __restrict__ bucketed)
{
    __shared__ int h[NBUCK];
    __shared__ int base[NBUCK];
    int b = blockIdx.x, t = threadIdx.x;
    for (int j = t; j < NBUCK; j += 256) {
        h[j] = 0;
        base[j] = cntT[(size_t)j * NBLK + b];
    }
    __syncthreads();
#pragma unroll
    for (int it = 0; it < 4; ++it) {
        int e4 = b * EPB + it * 1024 + t * 4;
        if (e4 < NE) {
            int4 s4 = *(const int4*)(ei + e4);
            int4 d4 = *(const int4*)(ei + NE + e4);
            float4 a01 = *(const float4*)(ea + 2 * (size_t)e4);
            float4 a23 = *(const float4*)(ea + 2 * (size_t)e4 + 4);
#define DO_EDGE(S, D, A0, A1)                                                \
            {                                                                \
                unsigned a0q = __float2uint_rn((A0) * 32768.0f);             \
                if (a0q > 32767u) a0q = 32767u;                              \
                unsigned a1q = __float2uint_rn((A1) * 32768.0f);             \
                if (a1q > 32767u) a1q = 32767u;                              \
                unsigned long long rec =                                     \
                      (((unsigned long long)(unsigned)(D)) << 47)            \
                    | (((unsigned long long)(unsigned)(S)) << 30)            \
                    | (((unsigned long long)a0q) << 15)                      \
                    | ((unsigned long long)a1q);                             \
                int bb = (D) >> 8;                                           \
                int lr = atomicAdd(&h[bb], 1);                               \
                bucketed[base[bb] + lr] = rec;                               \
            }
            DO_EDGE(s4.x, d4.x, a01.x, a01.y)
            DO_EDGE(s4.y, d4.y, a01.z, a01.w)
            DO_EDGE(s4.z, d4.z, a23.x, a23.y)
            DO_EDGE(s4.w, d4.w, a23.z, a23.w)
#undef DO_EDGE
        }
    }
}

// R3 FUSED: per-bucket finalize + expand + moments; inverse-permutation
// pass 2 iterates final positions -> coalesced A16/B8 writes (r19 win).
__global__ void __launch_bounds__(512)
__attribute__((amdgpu_waves_per_eu(2, 4))) finalize_kernel(
    const unsigned long long* __restrict__ bucketed,
    const int* __restrict__ cntT,
    const float* __restrict__ v,
    uint4* __restrict__ A16, uint2* __restrict__ B8,
    int* __restrict__ rowptr, int* __restrict__ pr, int* __restrict__ bhT,
    float* __restrict__ partials)   // [NBUCK][77]
{
    __shared__ int hist[256], lps[256], lh[64];
    __shared__ unsigned short pos16[MAXB];
    __shared__ unsigned char dl8[MAXB];
    __shared__ unsigned short inv16[MAXB];
    __shared__ float lsum[8][77];
    int b = blockIdx.x, t = threadIdx.x;
    if (t < 256) hist[t] = 0;
    if (t < 64) lh[t] = 0;
    __syncthreads();
    int bstart = cntT[(size_t)b * NBLK];
    int bend = (b == NBUCK - 1) ? NE : cntT[(size_t)(b + 1) * NBLK];
    int bsize = bend - bstart;

    for (int o = t; o < bsize; o += 512) {
        unsigned long long r = bucketed[bstart + o];
        int dl = (int)((r >> 47) & 255u);
        int lr = atomicAdd(&hist[dl], 1);
        pos16[o] = (unsigned short)lr;
        dl8[o] = (unsigned char)dl;
    }
    __syncthreads();
    int d = (t < 256) ? hist[t] : 0;
    if (t < 256) lps[t] = d;
    __syncthreads();
    for (int off = 1; off < 256; off <<= 1) {
        int val = (t >= off && t < 256) ? lps[t - off] : 0;
        __syncthreads();
        if (t < 256) lps[t] += val;
        __syncthreads();
    }
    int node = b * 256 + t;
    if (t < 256 && node < NN) {
        rowptr[node] = bstart + lps[t] - d;
        int db = d < 63 ? d : 63;
        int bkt = 63 - db;                   // descending degree (LPT)
        int lr2 = atomicAdd(&lh[bkt], 1);
        pr[node] = (lr2 << 6) | bkt;
    }
    if (b == 0 && t == 0) rowptr[NN] = NE;
    __syncthreads();
    if (t < 64) bhT[t * NBUCK + b] = lh[t];

    // invert the permutation: inv16[final_local_pos] = source offset
    for (int o = t; o < bsize; o += 512) {
        int dl = (int)dl8[o];
        int fp = (lps[dl] - hist[dl]) + (int)pos16[o];
        inv16[fp] = (unsigned short)o;
    }
    __syncthreads();

    // pass 2: iterate FINAL positions (coalesced writes), expand + moments
    float acc[39];
#pragma unroll
    for (int i = 0; i < 39; ++i) acc[i] = 0.0f;

    for (int p = t; (p - (t & 1)) < bsize; p += 512) {
        bool valid = p < bsize;
        float e[11];
        if (valid) {
            int o = (int)inv16[p];
            unsigned long long r = bucketed[bstart + o];   // L2-hot random read
            int dl = (int)((r >> 47) & 255u);
            int s = (int)((r >> 30) & 0x1FFFFu);
            float a0 = (float)(unsigned)((r >> 15) & 0x7FFFu) * (1.0f / 32768.0f);
            float a1 = (float)(unsigned)(r & 0x7FFFu) * (1.0f / 32768.0f);
            int dn = b * 256 + dl;
            float4 s0 = *(const float4*)(v + (size_t)s * 8);
            float4 s1 = *(const float4*)(v + (size_t)s * 8 + 4);
            float4 d0 = *(const float4*)(v + (size_t)dn * 8);
            float4 d1 = *(const float4*)(v + (size_t)dn * 8 + 4);
            float df[8];
            df[0] = d0.x - s0.x; df[1] = d0.y - s0.y;
            df[2] = d0.z - s0.z; df[3] = d0.w - s0.w;
            df[4] = d1.x - s1.x; df[5] = d1.y - s1.y;
            df[6] = d1.z - s1.z; df[7] = d1.w - s1.w;
            float nsq = 0.0f;
#pragma unroll
            for (int q = 0; q < 8; ++q) nsq = fmaf(df[q], df[q], nsq);
            float nrm = sqrtf(nsq);
            float inv = __builtin_amdgcn_rcpf(nrm + EPS_NORM);
            e[0] = a0; e[1] = a1; e[2] = nrm;
#pragma unroll
            for (int q = 0; q < 8; ++q) e[3 + q] = df[q] * inv;

            uint4 lo;
            lo.x = pk2(e[0], e[1]); lo.y = pk2(e[2], e[3]);
            lo.z = pk2(e[4], e[5]); lo.w = pk2(e[6], e[7]);
            A16[bstart + p] = lo;                     // coalesced
            unsigned q10 = __float2uint_rn((e[10] + 1.0f) * 16383.5f);
            if (q10 > 32767u) q10 = 32767u;
            uint2 hv;
            hv.x = pk2(e[8], e[9]);
            hv.y = ((unsigned)s << 15) | q10;
            B8[bstart + p] = hv;                      // coalesced
        } else {
#pragma unroll
            for (int k = 0; k < 11; ++k) e[k] = 0.0f;
        }
        float eo[11];
#pragma unroll
        for (int k = 0; k < 11; ++k) eo[k] = __shfl_xor(e[k], 1);
        if (!(t & 1)) {
#pragma unroll
            for (int k = 0; k < 11; ++k) acc[k] += e[k] + eo[k];
            int p2 = 11;
#pragma unroll
            for (int k = 0; k < 11; ++k)
#pragma unroll
                for (int l = k; l < 11; ++l) {
                    if (p2 < 39) {
                        acc[p2] = fmaf(e[k], e[l], acc[p2]);
                        acc[p2] = fmaf(eo[k], eo[l], acc[p2]);
                    }
                    ++p2;
                }
        } else {
            int p2 = 11;
#pragma unroll
            for (int k = 0; k < 11; ++k)
#pragma unroll
                for (int l = k; l < 11; ++l) {
                    if (p2 >= 39) {
                        acc[p2 - 39] = fmaf(e[k], e[l], acc[p2 - 39]);
                        acc[p2 - 39] = fmaf(eo[k], eo[l], acc[p2 - 39]);
                    }
                    ++p2;
                }
        }
    }

    // parity-preserving butterfly: lane0 sums even lanes, lane1 odd lanes.
#pragma unroll
    for (int i = 0; i < 39; ++i) {
        float x = acc[i];
        x += __shfl_down(x, 2);
        x += __shfl_down(x, 4);
        x += __shfl_down(x, 8);
        x += __shfl_down(x, 16);
        x += __shfl_down(x, 32);
        acc[i] = x;
    }
    int wave = t >> 6;
    int lane = t & 63;
    if (lane == 0) {
#pragma unroll
        for (int i = 0; i < 39; ++i) lsum[wave][i] = acc[i];
    }
    if (lane == 1) {
#pragma unroll
        for (int i = 0; i < 38; ++i) lsum[wave][39 + i] = acc[i];
    }
    __syncthreads();
    if (t < 77) {
        float s = 0.0f;
#pragma unroll
        for (int w = 0; w < 8; ++w) s += lsum[w][t];
        partials[b * 77 + t] = s;
    }
}

// BN closed-form; fold scale into W'/b'; emit f16-pair packed weights (5 rows).
__global__ void bn_finalize_kernel(
    const float* __restrict__ partials,
    const float* __restrict__ w0, const float* __restrict__ b0,
    const float* __restrict__ g0, const float* __restrict__ be0,
    const float* __restrict__ w1, const float* __restrict__ b1,
    const float* __restrict__ g1, const float* __restrict__ be1,
    float* __restrict__ wbp)   // layer l at +l*1152: W'[704], b'[64], pk[320]
{
    __shared__ double gs[77];
    int t = threadIdx.x;
    if (t < 77) {
        double s = 0.0;
        for (int b = 0; b < NBUCK; ++b) s += (double)partials[b * 77 + t];
        gs[t] = s;
    }
    __syncthreads();
    if (t >= 128) return;
    int layer = t >> 6;
    int c = t & 63;
    const float* W  = layer ? w1 : w0;
    const float* B  = layer ? b1 : b0;
    const float* G  = layer ? g1 : g0;
    const float* BE = layer ? be1 : be0;

    const double invE = 1.0 / (double)NE;
    double m[11], wv[11];
    for (int k = 0; k < 11; ++k) {
        m[k] = gs[k] * invE;
        wv[k] = (double)W[k * 64 + c];
    }
    double md = 0.0;
    for (int k = 0; k < 11; ++k) md += m[k] * wv[k];
    double s2 = 0.0;
    int p = 11;
    for (int k = 0; k < 11; ++k)
        for (int l = k; l < 11; ++l) {
            double Me = gs[p] * invE; ++p;
            double term = Me * wv[k] * wv[l];
            s2 += (k == l) ? term : 2.0 * term;
        }
    double var = s2 - md * md;
    double mu = md + (double)B[c];
    float scale = (float)((double)G[c] / sqrt(var + (double)EPS_BN));
    float shift = (float)((double)BE[c] - mu * (double)scale);

    float* wpd = wbp + layer * 1152;
    for (int k = 0; k < 11; ++k) wpd[k * 64 + c] = W[k * 64 + c] * scale;
    wpd[704 + c] = fmaf(B[c], scale, shift);
    unsigned* pw = (unsigned*)(wpd + 768);
    for (int kp = 0; kp < 5; ++kp) {
        float wlo = W[(2 * kp) * 64 + c] * scale;
        float whi = W[(2 * kp + 1) * 64 + c] * scale;
        pw[kp * 64 + c] = pk2(wlo, whi);
    }
}

__global__ void __launch_bounds__(256) permB_kernel(
    const int* __restrict__ pr, const int* __restrict__ bhT,
    const int* __restrict__ rowptr, int4* __restrict__ perm4)
{
    int n = blockIdx.x * 256 + threadIdx.x;
    if (n >= NN) return;
    int p = pr[n];
    int bkt = p & 63, lrank = p >> 6, b = n >> 8;
    int pos = bhT[bkt * NBUCK + b] + lrank;
    perm4[pos] = make_int4(n, rowptr[n], rowptr[n + 1], 0);
}

// Edge body: e-pairs from A16/B8 as u32, packed f16 weights + f32 row 10.
#define FAT_BODY3(LO, HB, E10, XI)                                           \
    do {                                                                     \
        _Pragma("unroll")                                                    \
        for (int o = 0; o < 8; ++o) {                                        \
            float hh = breg[o];                                              \
            hh = fdot2u((LO).x, pw[0][o], hh);                               \
            hh = fdot2u((LO).y, pw[1][o], hh);                               \
            hh = fdot2u((LO).z, pw[2][o], hh);                               \
            hh = fdot2u((LO).w, pw[3][o], hh);                               \
            hh = fdot2u((HB).x, pw[4][o], hh);                               \
            hh = fmaf((E10), w10[o], hh);                                    \
            msg[o] = fmaf((XI), fast_tanh(hh), msg[o]);                      \
        }                                                                    \
    } while (0)

// Per-layer fused gather-message + mean + root + lrelu (+residual).
template<int LAYER>
__global__ void __launch_bounds__(256)
__attribute__((amdgpu_waves_per_eu(2, 6))) layer_fat_kernel(
    const float* __restrict__ vres,
    const float* __restrict__ x,
    const uint4* __restrict__ A16, const uint2* __restrict__ B8,
    const int4* __restrict__ perm4,
    const float* __restrict__ wb,   // layer base: W'f32[704], b'[64], pk[320]
    const float* __restrict__ rw, const float* __restrict__ rb,
    float* __restrict__ out)
{
    int g = blockIdx.x * 256 + threadIdx.x;
    int4 pm = perm4[g >> 3];
    int n = pm.x, rp0 = pm.y, rp1 = pm.z;
    int i = g & 7;

    unsigned pw[5][8];
    const unsigned* pwg = (const unsigned*)(wb + 768);
#pragma unroll
    for (int kp = 0; kp < 5; ++kp) {
        uint4 pa = *(const uint4*)(pwg + kp * 64 + i * 8);
        uint4 pb = *(const uint4*)(pwg + kp * 64 + i * 8 + 4);
        pw[kp][0] = pa.x; pw[kp][1] = pa.y; pw[kp][2] = pa.z; pw[kp][3] = pa.w;
        pw[kp][4] = pb.x; pw[kp][5] = pb.y; pw[kp][6] = pb.z; pw[kp][7] = pb.w;
    }
    float w10[8];
    {
        float4 wa = *(const float4*)(wb + 640 + i * 8);
        float4 wc = *(const float4*)(wb + 640 + i * 8 + 4);
        w10[0] = wa.x; w10[1] = wa.y; w10[2] = wa.z; w10[3] = wa.w;
        w10[4] = wc.x; w10[5] = wc.y; w10[6] = wc.z; w10[7] = wc.w;
    }
    float breg[8];
    {
        float4 ba = *(const float4*)(wb + 704 + i * 8);
        float4 bb = *(const float4*)(wb + 704 + i * 8 + 4);
        breg[0] = ba.x; breg[1] = ba.y; breg[2] = ba.z; breg[3] = ba.w;
        breg[4] = bb.x; breg[5] = bb.y; breg[6] = bb.z; breg[7] = bb.w;
    }

    float4 vd0 = *(const float4*)(vres + (size_t)n * 8);
    float4 vd1 = *(const float4*)(vres + (size_t)n * 8 + 4);
    float vd[8] = {vd0.x, vd0.y, vd0.z, vd0.w, vd1.x, vd1.y, vd1.z, vd1.w};

    float msg[8];
#pragma unroll
    for (int o = 0; o < 8; ++o) msg[o] = 0.0f;

    int j = rp0;
    for (; j + 2 <= rp1; j += 2) {
        uint4 lo0 = A16[j];
        uint4 lo1 = A16[j + 1];
        uint2 hb0 = B8[j];
        uint2 hb1 = B8[j + 1];
        int s0 = (int)(hb0.y >> 15);
        int s1 = (int)(hb1.y >> 15);
        float e10a = fmaf((float)(hb0.y & 0x7FFFu), 1.0f / 16383.5f, -1.0f);
        float e10b = fmaf((float)(hb1.y & 0x7FFFu), 1.0f / 16383.5f, -1.0f);
        float xi0 = x[(size_t)s0 * 8 + i];
        float xi1 = x[(size_t)s1 * 8 + i];
        FAT_BODY3(lo0, hb0, e10a, xi0);
        FAT_BODY3(lo1, hb1, e10b, xi1);
    }
    if (j < rp1) {
        uint4 lo0 = A16[j];
        uint2 hb0 = B8[j];
        int s0 = (int)(hb0.y >> 15);
        float e10a = fmaf((float)(hb0.y & 0x7FFFu), 1.0f / 16383.5f, -1.0f);
        float xi0 = x[(size_t)s0 * 8 + i];
        FAT_BODY3(lo0, hb0, e10a, xi0);
    }

#pragma unroll
    for (int o = 0; o < 8; ++o) {
        float m = msg[o];
        m += __shfl_xor(m, 1);
        m += __shfl_xor(m, 2);
        m += __shfl_xor(m, 4);
        msg[o] = m;
    }
    float mo = msg[0];
#pragma unroll
    for (int o = 1; o < 8; ++o) if (i == o) mo = msg[o];

    float cf = (float)(rp1 - rp0);
    float invc = __builtin_amdgcn_rcpf(fmaxf(cf, 1.0f));

    float xn[8];
    if (LAYER == 0) {
#pragma unroll
        for (int q = 0; q < 8; ++q) xn[q] = vd[q];
    } else {
        float4 x0 = *(const float4*)(x + (size_t)n * 8);
        float4 x1 = *(const float4*)(x + (size_t)n * 8 + 4);
        xn[0] = x0.x; xn[1] = x0.y; xn[2] = x0.z; xn[3] = x0.w;
        xn[4] = x1.x; xn[5] = x1.y; xn[6] = x1.z; xn[7] = x1.w;
    }
    float a = fmaf(mo, invc, rb[i]);
#pragma unroll
    for (int k = 0; k < 8; ++k) a = fmaf(xn[k], rw[k * 8 + i], a);
    float y = (a > 0.0f) ? a : SLOPE * a;
    if (LAYER == 1) y += vres[(size_t)n * 8 + i];
    out[(size_t)n * 8 + i] = y;
}

extern "C" void kernel_launch(void* const* d_in, const int* in_sizes, int n_in,
                              void* d_out, int out_size, void* d_ws, size_t ws_size,
                              hipStream_t stream) {
    const float* v  = (const float*)d_in[0];
    const int* ei   = (const int*)d_in[1];
    const float* ea = (const float*)d_in[2];
    const float* en_w0  = (const float*)d_in[3];
    const float* en_b0  = (const float*)d_in[4];
    const float* en_g0  = (const float*)d_in[5];
    const float* en_be0 = (const float*)d_in[6];
    const float* rw0    = (const float*)d_in[7];
    const float* rb0    = (const float*)d_in[8];
    const float* en_w1  = (const float*)d_in[9];
    const float* en_b1  = (const float*)d_in[10];
    const float* en_g1  = (const float*)d_in[11];
    const float* en_be1 = (const float*)d_in[12];
    const float* rw1    = (const float*)d_in[13];
    const float* rb1    = (const float*)d_in[14];

    char* ws = (char*)d_ws;
    float* partials = (float*)(ws);                    // 120,428 B
    float* wbp      = (float*)(ws + 131072);           // 9,216 B
    int*   rowptr   = (int*)  (ws + 143360);           // 400,004 B
    int*   pr       = (int*)  (ws + 543744);           // 400,000 B
    int4*  perm4    = (int4*) (ws + 944128);           // 1,600,000 B
    int*   bhT      = (int*)  (ws + 2544128);          // 100,096 B
    int*   gbsum    = (int*)  (ws + 2644224);          // 392 B
    int*   cbsum    = (int*)  (ws + 2644736);          // 2,392 B
    int*   cntT     = (int*)  (ws + 2648064);          // 611,524 B
    float* v1       = (float*)(ws + 3259904);          // 3,200,000 B
    unsigned long long* bucketed = (unsigned long long*)(ws + 6460416); // 12.8 MB
    uint4* A16      = (uint4*)(ws + 19260416);         // 25.6 MB
    uint2* B8       = (uint2*)(ws + 44860416);         // 12.8 MB -> 57,660,416
    float* vout     = (float*)d_out;

    r1_count_kernel<<<NBLK, 256, 0, stream>>>(ei, cntT);
    gscanA_kernel<<<CSB, 256, 0, stream>>>(cntT, cbsum, CNT_LEN);
    gscanB_kernel<<<CSB, 256, 0, stream>>>(cntT, cbsum, CNT_LEN);
    r2_scatter_kernel<<<NBLK, 256, 0, stream>>>(ei, ea, cntT, bucketed);
    finalize_kernel<<<NBUCK, 512, 0, stream>>>(bucketed, cntT, v, A16, B8,
                                               rowptr, pr, bhT, partials);
    gscanA_kernel<<<GS_BLOCKS, 256, 0, stream>>>(bhT, gbsum, GS_LEN);
    gscanB_kernel<<<GS_BLOCKS, 256, 0, stream>>>(bhT, gbsum, GS_LEN);
    permB_kernel<<<NBUCK, 256, 0, stream>>>(pr, bhT, rowptr, perm4);
    bn_finalize_kernel<<<1, 128, 0, stream>>>(partials, en_w0, en_b0, en_g0, en_be0,
                                              en_w1, en_b1, en_g1, en_be1, wbp);

    const int LB = (NN * 8) / 256;   // 3125, exact
    layer_fat_kernel<0><<<LB, 256, 0, stream>>>(v, v,  A16, B8, perm4, wbp,        rw0, rb0, v1);
    layer_fat_kernel<1><<<LB, 256, 0, stream>>>(v, v1, A16, B8, perm4, wbp + 1152, rw1, rb1, vout);
}

// Round 21
// 200.084 us; speedup vs baseline: 1.1278x; 1.0081x over previous
//
#include <hip/hip_runtime.h>
#include <hip/hip_fp16.h>
#include <math.h>

#define NN 100000
#define NE 1600000
#define EPS_BN 1e-5f
#define EPS_NORM 1e-12f
#define SLOPE 0.01f
#define NBUCK 391                            // = ceil(NN/256); bucket = dst>>8
#define NBLK 391                             // edge-chunk blocks (4096 edges each)
#define EPB 4096                             // edges per r1/r2 block
#define CNT_LEN (NBUCK * NBLK)               // 152,881
#define CSB ((CNT_LEN + 255) / 256)          // 598
#define GS_LEN (64 * NBUCK)                  // 25024
#define GS_BLOCKS ((GS_LEN + 255) / 256)     // 98
#define MAXB 6144                            // max edges/bucket (Poisson(4096)+slack)

typedef _Float16 h2 __attribute__((ext_vector_type(2)));

#if __has_builtin(__builtin_amdgcn_exp2f)
#define EXP2F(x) __builtin_amdgcn_exp2f(x)
#else
#define EXP2F(x) exp2f(x)
#endif

__device__ __forceinline__ float fast_tanh(float x) {
    float t = EXP2F(x * 2.885390082f);
    return fmaf(-2.0f, __builtin_amdgcn_rcpf(t + 1.0f), 1.0f);
}

__device__ __forceinline__ unsigned pk2(float a, float b) {
    union { __half2 h; unsigned u; } c;
    c.h = __float22half2_rn(make_float2(a, b));
    return c.u;
}

#if __has_builtin(__builtin_amdgcn_fdot2)
__device__ __forceinline__ float fdot2u(unsigned a, unsigned b, float c) {
    union { unsigned u; h2 h; } ca, cb;
    ca.u = a; cb.u = b;
    return __builtin_amdgcn_fdot2(ca.h, cb.h, c, false);
}
#else
__device__ __forceinline__ float fdot2u(unsigned a, unsigned b, float c) {
    float d;
    asm("v_dot2_f32_f16 %0, %1, %2, %3" : "=v"(d) : "v"(a), "v"(b), "v"(c));
    return d;
}
#endif

// R1: per-block LDS bucket histogram over 4096 edges (bucket = dst>>8).
__global__ void __launch_bounds__(256) r1_count_kernel(
    const int* __restrict__ ei, int* __restrict__ cntT)
{
    __shared__ int h[NBUCK];
    int b = blockIdx.x, t = threadIdx.x;
    for (int j = t; j < NBUCK; j += 256) h[j] = 0;
    __syncthreads();
#pragma unroll
    for (int it = 0; it < 4; ++it) {
        int e4 = b * EPB + it * 1024 + t * 4;
        if (e4 < NE) {
            int4 d4 = *(const int4*)(ei + NE + e4);
            atomicAdd(&h[d4.x >> 8], 1);
            atomicAdd(&h[d4.y >> 8], 1);
            atomicAdd(&h[d4.z >> 8], 1);
            atomicAdd(&h[d4.w >> 8], 1);
        }
    }
    __syncthreads();
    for (int j = t; j < NBUCK; j += 256) cntT[(size_t)j * NBLK + b] = h[j];
}

// Generic 2-level exclusive scan (block pass + offset pass), length-param'd.
__global__ void __launch_bounds__(256) gscanA_kernel(
    int* __restrict__ a, int* __restrict__ bs, int len)
{
    int b = blockIdx.x, t = threadIdx.x;
    int i = b * 256 + t;
    int d = (i < len) ? a[i] : 0;
    __shared__ int sh[256];
    sh[t] = d;
    __syncthreads();
    for (int off = 1; off < 256; off <<= 1) {
        int val = (t >= off) ? sh[t - off] : 0;
        __syncthreads();
        sh[t] += val;
        __syncthreads();
    }
    if (i < len) a[i] = sh[t] - d;
    if (t == 255) bs[b] = sh[255];
}

__global__ void __launch_bounds__(256) gscanB_kernel(
    int* __restrict__ a, const int* __restrict__ bs, int len)
{
    int b = blockIdx.x, t = threadIdx.x;
    __shared__ int sh[256];
    int s = 0;
    for (int j = t; j < b; j += 256) s += bs[j];
    sh[t] = s;
    __syncthreads();
    for (int off = 128; off > 0; off >>= 1) {
        if (t < off) sh[t] += sh[t + off];
        __syncthreads();
    }
    int boff = sh[0];
    int i = b * 256 + t;
    if (i < len) a[i] += boff;
}

// R2: bucket-scatter packed recs [dst:17|src:17|a0:15|a1:15] via LDS ranks.
__global__ void __launch_bounds__(256) r2_scatter_kernel(
    const int* __restrict__ ei, const float* __restrict__ ea,
    const int* __restrict__ cntT, unsigned long long* __restrict__ bucketed)
{
    __shared__ int h[NBUCK];
    __shared__ int base[NBUCK];
    int b = blockIdx.x, t = threadIdx.x;
    for (int j = t; j < NBUCK; j += 256) {
        h[j] = 0;
        base[j] = cntT[(size_t)j * NBLK + b];
    }
    __syncthreads();
#pragma unroll
    for (int it = 0; it < 4; ++it) {
        int e4 = b * EPB + it * 1024 + t * 4;
        if (e4 < NE) {
            int4 s4 = *(const int4*)(ei + e4);
            int4 d4 = *(const int4*)(ei + NE + e4);
            float4 a01 = *(const float4*)(ea + 2 * (size_t)e4);
            float4 a23 = *(const float4*)(ea + 2 * (size_t)e4 + 4);
#define DO_EDGE(S, D, A0, A1)                                                \
            {                                                                \
                unsigned a0q = __float2uint_rn((A0) * 32768.0f);             \
                if (a0q > 32767u) a0q = 32767u;                              \
                unsigned a1q = __float2uint_rn((A1) * 32768.0f);             \
                if (a1q > 32767u) a1q = 32767u;                              \
                unsigned long long rec =                                     \
                      (((unsigned long long)(unsigned)(D)) << 47)            \
                    | (((unsigned long long)(unsigned)(S)) << 30)            \
                    | (((unsigned long long)a0q) << 15)                      \
                    | ((unsigned long long)a1q);                             \
                int bb = (D) >> 8;                                           \
                int lr = atomicAdd(&h[bb], 1);                               \
                bucketed[base[bb] + lr] = rec;                               \
            }
            DO_EDGE(s4.x, d4.x, a01.x, a01.y)
            DO_EDGE(s4.y, d4.y, a01.z, a01.w)
            DO_EDGE(s4.z, d4.z, a23.x, a23.y)
            DO_EDGE(s4.w, d4.w, a23.z, a23.w)
#undef DO_EDGE
        }
    }
}

// R3 FUSED: per-bucket finalize + expand + moments; inverse-permutation
// pass 2 iterates final positions -> coalesced A16/B8 writes (r19 win).
__global__ void __launch_bounds__(512)
__attribute__((amdgpu_waves_per_eu(2, 4))) finalize_kernel(
    const unsigned long long* __restrict__ bucketed,
    const int* __restrict__ cntT,
    const float* __restrict__ v,
    uint4* __restrict__ A16, uint2* __restrict__ B8,
    int* __restrict__ rowptr, int* __restrict__ pr, int* __restrict__ bhT,
    float* __restrict__ partials)   // [NBUCK][77]
{
    __shared__ int hist[256], lps[256], lh[64];
    __shared__ unsigned short pos16[MAXB];
    __shared__ unsigned char dl8[MAXB];
    __shared__ unsigned short inv16[MAXB];
    __shared__ float lsum[8][77];
    int b = blockIdx.x, t = threadIdx.x;
    if (t < 256) hist[t] = 0;
    if (t < 64) lh[t] = 0;
    __syncthreads();
    int bstart = cntT[(size_t)b * NBLK];
    int bend = (b == NBUCK - 1) ? NE : cntT[(size_t)(b + 1) * NBLK];
    int bsize = bend - bstart;

    for (int o = t; o < bsize; o += 512) {
        unsigned long long r = bucketed[bstart + o];
        int dl = (int)((r >> 47) & 255u);
        int lr = atomicAdd(&hist[dl], 1);
        pos16[o] = (unsigned short)lr;
        dl8[o] = (unsigned char)dl;
    }
    __syncthreads();
    int d = (t < 256) ? hist[t] : 0;
    if (t < 256) lps[t] = d;
    __syncthreads();
    for (int off = 1; off < 256; off <<= 1) {
        int val = (t >= off && t < 256) ? lps[t - off] : 0;
        __syncthreads();
        if (t < 256) lps[t] += val;
        __syncthreads();
    }
    int node = b * 256 + t;
    if (t < 256 && node < NN) {
        rowptr[node] = bstart + lps[t] - d;
        int db = d < 63 ? d : 63;
        int bkt = 63 - db;                   // descending degree (LPT)
        int lr2 = atomicAdd(&lh[bkt], 1);
        pr[node] = (lr2 << 6) | bkt;
    }
    if (b == 0 && t == 0) rowptr[NN] = NE;
    __syncthreads();
    if (t < 64) bhT[t * NBUCK + b] = lh[t];

    // invert the permutation: inv16[final_local_pos] = source offset
    for (int o = t; o < bsize; o += 512) {
        int dl = (int)dl8[o];
        int fp = (lps[dl] - hist[dl]) + (int)pos16[o];
        inv16[fp] = (unsigned short)o;
    }
    __syncthreads();

    // pass 2: iterate FINAL positions (coalesced writes), expand + moments
    float acc[39];
#pragma unroll
    for (int i = 0; i < 39; ++i) acc[i] = 0.0f;

    for (int p = t; (p - (t & 1)) < bsize; p += 512) {
        bool valid = p < bsize;
        float e[11];
        if (valid) {
            int o = (int)inv16[p];
            unsigned long long r = bucketed[bstart + o];   // L2-hot random read
            int dl = (int)((r >> 47) & 255u);
            int s = (int)((r >> 30) & 0x1FFFFu);
            float a0 = (float)(unsigned)((r >> 15) & 0x7FFFu) * (1.0f / 32768.0f);
            float a1 = (float)(unsigned)(r & 0x7FFFu) * (1.0f / 32768.0f);
            int dn = b * 256 + dl;
            float4 s0 = *(const float4*)(v + (size_t)s * 8);
            float4 s1 = *(const float4*)(v + (size_t)s * 8 + 4);
            float4 d0 = *(const float4*)(v + (size_t)dn * 8);
            float4 d1 = *(const float4*)(v + (size_t)dn * 8 + 4);
            float df[8];
            df[0] = d0.x - s0.x; df[1] = d0.y - s0.y;
            df[2] = d0.z - s0.z; df[3] = d0.w - s0.w;
            df[4] = d1.x - s1.x; df[5] = d1.y - s1.y;
            df[6] = d1.z - s1.z; df[7] = d1.w - s1.w;
            float nsq = 0.0f;
#pragma unroll
            for (int q = 0; q < 8; ++q) nsq = fmaf(df[q], df[q], nsq);
            float nrm = sqrtf(nsq);
            float inv = __builtin_amdgcn_rcpf(nrm + EPS_NORM);
            e[0] = a0; e[1] = a1; e[2] = nrm;
#pragma unroll
            for (int q = 0; q < 8; ++q) e[3 + q] = df[q] * inv;

            uint4 lo;
            lo.x = pk2(e[0], e[1]); lo.y = pk2(e[2], e[3]);
            lo.z = pk2(e[4], e[5]); lo.w = pk2(e[6], e[7]);
            A16[bstart + p] = lo;                     // coalesced
            unsigned q10 = __float2uint_rn((e[10] + 1.0f) * 16383.5f);
            if (q10 > 32767u) q10 = 32767u;
            uint2 hv;
            hv.x = pk2(e[8], e[9]);
            hv.y = ((unsigned)s << 15) | q10;
            B8[bstart + p] = hv;                      // coalesced
        } else {
#pragma unroll
            for (int k = 0; k < 11; ++k) e[k] = 0.0f;
        }
        float eo[11];
#pragma unroll
        for (int k = 0; k < 11; ++k) eo[k] = __shfl_xor(e[k], 1);
        if (!(t & 1)) {
#pragma unroll
            for (int k = 0; k < 11; ++k) acc[k] += e[k] + eo[k];
            int p2 = 11;
#pragma unroll
            for (int k = 0; k < 11; ++k)
#pragma unroll
                for (int l = k; l < 11; ++l) {
                    if (p2 < 39) {
                        acc[p2] = fmaf(e[k], e[l], acc[p2]);
                        acc[p2] = fmaf(eo[k], eo[l], acc[p2]);
                    }
                    ++p2;
                }
        } else {
            int p2 = 11;
#pragma unroll
            for (int k = 0; k < 11; ++k)
#pragma unroll
                for (int l = k; l < 11; ++l) {
                    if (p2 >= 39) {
                        acc[p2 - 39] = fmaf(e[k], e[l], acc[p2 - 39]);
                        acc[p2 - 39] = fmaf(eo[k], eo[l], acc[p2 - 39]);
                    }
                    ++p2;
                }
        }
    }

    // parity-preserving butterfly: lane0 sums even lanes, lane1 odd lanes.
#pragma unroll
    for (int i = 0; i < 39; ++i) {
        float x = acc[i];
        x += __shfl_down(x, 2);
        x += __shfl_down(x, 4);
        x += __shfl_down(x, 8);
        x += __shfl_down(x, 16);
        x += __shfl_down(x, 32);
        acc[i] = x;
    }
    int wave = t >> 6;
    int lane = t & 63;
    if (lane == 0) {
#pragma unroll
        for (int i = 0; i < 39; ++i) lsum[wave][i] = acc[i];
    }
    if (lane == 1) {
#pragma unroll
        for (int i = 0; i < 38; ++i) lsum[wave][39 + i] = acc[i];
    }
    __syncthreads();
    if (t < 77) {
        float s = 0.0f;
#pragma unroll
        for (int w = 0; w < 8; ++w) s += lsum[w][t];
        partials[b * 77 + t] = s;
    }
}

// BN closed-form; fold scale into W'/b'; emit f16-pair packed weights (5 rows).
__global__ void bn_finalize_kernel(
    const float* __restrict__ partials,
    const float* __restrict__ w0, const float* __restrict__ b0,
    const float* __restrict__ g0, const float* __restrict__ be0,
    const float* __restrict__ w1, const float* __restrict__ b1,
    const float* __restrict__ g1, const float* __restrict__ be1,
    float* __restrict__ wbp)   // layer l at +l*1152: W'[704], b'[64], pk[320]
{
    __shared__ double gs[77];
    int t = threadIdx.x;
    if (t < 77) {
        double s = 0.0;
        for (int b = 0; b < NBUCK; ++b) s += (double)partials[b * 77 + t];
        gs[t] = s;
    }
    __syncthreads();
    if (t >= 128) return;
    int layer = t >> 6;
    int c = t & 63;
    const float* W  = layer ? w1 : w0;
    const float* B  = layer ? b1 : b0;
    const float* G  = layer ? g1 : g0;
    const float* BE = layer ? be1 : be0;

    const double invE = 1.0 / (double)NE;
    double m[11], wv[11];
    for (int k = 0; k < 11; ++k) {
        m[k] = gs[k] * invE;
        wv[k] = (double)W[k * 64 + c];
    }
    double md = 0.0;
    for (int k = 0; k < 11; ++k) md += m[k] * wv[k];
    double s2 = 0.0;
    int p = 11;
    for (int k = 0; k < 11; ++k)
        for (int l = k; l < 11; ++l) {
            double Me = gs[p] * invE; ++p;
            double term = Me * wv[k] * wv[l];
            s2 += (k == l) ? term : 2.0 * term;
        }
    double var = s2 - md * md;
    double mu = md + (double)B[c];
    float scale = (float)((double)G[c] / sqrt(var + (double)EPS_BN));
    float shift = (float)((double)BE[c] - mu * (double)scale);

    float* wpd = wbp + layer * 1152;
    for (int k = 0; k < 11; ++k) wpd[k * 64 + c] = W[k * 64 + c] * scale;
    wpd[704 + c] = fmaf(B[c], scale, shift);
    unsigned* pw = (unsigned*)(wpd + 768);
    for (int kp = 0; kp < 5; ++kp) {
        float wlo = W[(2 * kp) * 64 + c] * scale;
        float whi = W[(2 * kp + 1) * 64 + c] * scale;
        pw[kp * 64 + c] = pk2(wlo, whi);
    }
}

__global__ void __launch_bounds__(256) permB_kernel(
    const int* __restrict__ pr, const int* __restrict__ bhT,
    const int* __restrict__ rowptr, int4* __restrict__ perm4)
{
    int n = blockIdx.x * 256 + threadIdx.x;
    if (n >= NN) return;
    int p = pr[n];
    int bkt = p & 63, lrank = p >> 6, b = n >> 8;
    int pos = bhT[bkt * NBUCK + b] + lrank;
    perm4[pos] = make_int4(n, rowptr[n], rowptr[n + 1], 0);
}

// Edge body: e-pairs from A16/B8 as u32, packed f16 weights + f32 row 10.
#define FAT_BODY3(LO, HB, E10, XI)                                           \
    do {                                                                     \
        _Pragma("unroll")                                                    \
        for (int o = 0; o < 8; ++o) {                                        \
            float hh = breg[o];                                              \
            hh = fdot2u((LO).x, pw[0][o], hh);                               \
            hh = fdot2u((LO).y, pw[1][o], hh);                               \
            hh = fdot2u((LO).z, pw[2][o], hh);                               \
            hh = fdot2u((LO).w, pw[3][o], hh);                               \
            hh = fdot2u((HB).x, pw[4][o], hh);                               \
            hh = fmaf((E10), w10[o], hh);                                    \
            msg[o] = fmaf((XI), fast_tanh(hh), msg[o]);                      \
        }                                                                    \
    } while (0)

// Per-layer fused gather-message + mean + root + lrelu (+residual).
// r20 diagnosis: VGPR_Count=52 < 56 declared weight dwords -> the compiler
// REMATERIALIZES all weight loads inside the edge loop (~224B/lane/edge of
// L1 traffic; kernel is L1-BW-bound, not VALU-bound). Fix: asm opacity
// fence after the loads (un-rematerializable) + waves_per_eu(1,4) budget.
template<int LAYER>
__global__ void __launch_bounds__(256)
__attribute__((amdgpu_waves_per_eu(1, 4))) layer_fat_kernel(
    const float* __restrict__ vres,
    const float* __restrict__ x,
    const uint4* __restrict__ A16, const uint2* __restrict__ B8,
    const int4* __restrict__ perm4,
    const float* __restrict__ wb,   // layer base: W'f32[704], b'[64], pk[320]
    const float* __restrict__ rw, const float* __restrict__ rb,
    float* __restrict__ out)
{
    int g = blockIdx.x * 256 + threadIdx.x;
    int4 pm = perm4[g >> 3];
    int n = pm.x, rp0 = pm.y, rp1 = pm.z;
    int i = g & 7;

    unsigned pw[5][8];
    const unsigned* pwg = (const unsigned*)(wb + 768);
#pragma unroll
    for (int kp = 0; kp < 5; ++kp) {
        uint4 pa = *(const uint4*)(pwg + kp * 64 + i * 8);
        uint4 pb = *(const uint4*)(pwg + kp * 64 + i * 8 + 4);
        pw[kp][0] = pa.x; pw[kp][1] = pa.y; pw[kp][2] = pa.z; pw[kp][3] = pa.w;
        pw[kp][4] = pb.x; pw[kp][5] = pb.y; pw[kp][6] = pb.z; pw[kp][7] = pb.w;
    }
    float w10[8];
    {
        float4 wa = *(const float4*)(wb + 640 + i * 8);
        float4 wc = *(const float4*)(wb + 640 + i * 8 + 4);
        w10[0] = wa.x; w10[1] = wa.y; w10[2] = wa.z; w10[3] = wa.w;
        w10[4] = wc.x; w10[5] = wc.y; w10[6] = wc.z; w10[7] = wc.w;
    }
    float breg[8];
    {
        float4 ba = *(const float4*)(wb + 704 + i * 8);
        float4 bb = *(const float4*)(wb + 704 + i * 8 + 4);
        breg[0] = ba.x; breg[1] = ba.y; breg[2] = ba.z; breg[3] = ba.w;
        breg[4] = bb.x; breg[5] = bb.y; breg[6] = bb.z; breg[7] = bb.w;
    }
    // Opacity fence: defs become asm outputs -> cannot be rematerialized;
    // the allocator must keep these 56 dwords resident across the loop.
#pragma unroll
    for (int kp = 0; kp < 5; ++kp)
#pragma unroll
        for (int o = 0; o < 8; ++o)
            asm volatile("" : "+v"(pw[kp][o]));
#pragma unroll
    for (int o = 0; o < 8; ++o) {
        asm volatile("" : "+v"(w10[o]));
        asm volatile("" : "+v"(breg[o]));
    }

    float4 vd0 = *(const float4*)(vres + (size_t)n * 8);
    float4 vd1 = *(const float4*)(vres + (size_t)n * 8 + 4);
    float vd[8] = {vd0.x, vd0.y, vd0.z, vd0.w, vd1.x, vd1.y, vd1.z, vd1.w};

    float msg[8];
#pragma unroll
    for (int o = 0; o < 8; ++o) msg[o] = 0.0f;

    int j = rp0;
    for (; j + 2 <= rp1; j += 2) {
        uint4 lo0 = A16[j];
        uint4 lo1 = A16[j + 1];
        uint2 hb0 = B8[j];
        uint2 hb1 = B8[j + 1];
        int s0 = (int)(hb0.y >> 15);
        int s1 = (int)(hb1.y >> 15);
        float e10a = fmaf((float)(hb0.y & 0x7FFFu), 1.0f / 16383.5f, -1.0f);
        float e10b = fmaf((float)(hb1.y & 0x7FFFu), 1.0f / 16383.5f, -1.0f);
        float xi0 = x[(size_t)s0 * 8 + i];
        float xi1 = x[(size_t)s1 * 8 + i];
        FAT_BODY3(lo0, hb0, e10a, xi0);
        FAT_BODY3(lo1, hb1, e10b, xi1);
    }
    if (j < rp1) {
        uint4 lo0 = A16[j];
        uint2 hb0 = B8[j];
        int s0 = (int)(hb0.y >> 15);
        float e10a = fmaf((float)(hb0.y & 0x7FFFu), 1.0f / 16383.5f, -1.0f);
        float xi0 = x[(size_t)s0 * 8 + i];
        FAT_BODY3(lo0, hb0, e10a, xi0);
    }

#pragma unroll
    for (int o = 0; o < 8; ++o) {
        float m = msg[o];
        m += __shfl_xor(m, 1);
        m += __shfl_xor(m, 2);
        m += __shfl_xor(m, 4);
        msg[o] = m;
    }
    float mo = msg[0];
#pragma unroll
    for (int o = 1; o < 8; ++o) if (i == o) mo = msg[o];

    float cf = (float)(rp1 - rp0);
    float invc = __builtin_amdgcn_rcpf(fmaxf(cf, 1.0f));

    float xn[8];
    if (LAYER == 0) {
#pragma unroll
        for (int q = 0; q < 8; ++q) xn[q] = vd[q];
    } else {
        float4 x0 = *(const float4*)(x + (size_t)n * 8);
        float4 x1 = *(const float4*)(x + (size_t)n * 8 + 4);
        xn[0] = x0.x; xn[1] = x0.y; xn[2] = x0.z; xn[3] = x0.w;
        xn[4] = x1.x; xn[5] = x1.y; xn[6] = x1.z; xn[7] = x1.w;
    }
    float a = fmaf(mo, invc, rb[i]);
#pragma unroll
    for (int k = 0; k < 8; ++k) a = fmaf(xn[k], rw[k * 8 + i], a);
    float y = (a > 0.0f) ? a : SLOPE * a;
    if (LAYER == 1) y += vres[(size_t)n * 8 + i];
    out[(size_t)n * 8 + i] = y;
}

extern "C" void kernel_launch(void* const* d_in, const int* in_sizes, int n_in,
                              void* d_out, int out_size, void* d_ws, size_t ws_size,
                              hipStream_t stream) {
    const float* v  = (const float*)d_in[0];
    const int* ei   = (const int*)d_in[1];
    const float* ea = (const float*)d_in[2];
    const float* en_w0  = (const float*)d_in[3];
    const float* en_b0  = (const float*)d_in[4];
    const float* en_g0  = (const float*)d_in[5];
    const float* en_be0 = (const float*)d_in[6];
    const float* rw0    = (const float*)d_in[7];
    const float* rb0    = (const float*)d_in[8];
    const float* en_w1  = (const float*)d_in[9];
    const float* en_b1  = (const float*)d_in[10];
    const float* en_g1  = (const float*)d_in[11];
    const float* en_be1 = (const float*)d_in[12];
    const float* rw1    = (const float*)d_in[13];
    const float* rb1    = (const float*)d_in[14];

    char* ws = (char*)d_ws;
    float* partials = (float*)(ws);                    // 120,428 B
    float* wbp      = (float*)(ws + 131072);           // 9,216 B
    int*   rowptr   = (int*)  (ws + 143360);           // 400,004 B
    int*   pr       = (int*)  (ws + 543744);           // 400,000 B
    int4*  perm4    = (int4*) (ws + 944128);           // 1,600,000 B
    int*   bhT      = (int*)  (ws + 2544128);          // 100,096 B
    int*   gbsum    = (int*)  (ws + 2644224);          // 392 B
    int*   cbsum    = (int*)  (ws + 2644736);          // 2,392 B
    int*   cntT     = (int*)  (ws + 2648064);          // 611,524 B
    float* v1       = (float*)(ws + 3259904);          // 3,200,000 B
    unsigned long long* bucketed = (unsigned long long*)(ws + 6460416); // 12.8 MB
    uint4* A16      = (uint4*)(ws + 19260416);         // 25.6 MB
    uint2* B8       = (uint2*)(ws + 44860416);         // 12.8 MB -> 57,660,416
    float* vout     = (float*)d_out;

    r1_count_kernel<<<NBLK, 256, 0, stream>>>(ei, cntT);
    gscanA_kernel<<<CSB, 256, 0, stream>>>(cntT, cbsum, CNT_LEN);
    gscanB_kernel<<<CSB, 256, 0, stream>>>(cntT, cbsum, CNT_LEN);
    r2_scatter_kernel<<<NBLK, 256, 0, stream>>>(ei, ea, cntT, bucketed);
    finalize_kernel<<<NBUCK, 512, 0, stream>>>(bucketed, cntT, v, A16, B8,
                                               rowptr, pr, bhT, partials);
    gscanA_kernel<<<GS_BLOCKS, 256, 0, stream>>>(bhT, gbsum, GS_LEN);
    gscanB_kernel<<<GS_BLOCKS, 256, 0, stream>>>(bhT, gbsum, GS_LEN);
    permB_kernel<<<NBUCK, 256, 0, stream>>>(pr, bhT, rowptr, perm4);
    bn_finalize_kernel<<<1, 128, 0, stream>>>(partials, en_w0, en_b0, en_g0, en_be0,
                                              en_w1, en_b1, en_g1, en_be1, wbp);

    const int LB = (NN * 8) / 256;   // 3125, exact
    layer_fat_kernel<0><<<LB, 256, 0, stream>>>(v, v,  A16, B8, perm4, wbp,        rw0, rb0, v1);
    layer_fat_kernel<1><<<LB, 256, 0, stream>>>(v, v1, A16, B8, perm4, wbp + 1152, rw1, rb1, vout);
}